// Round 17
// baseline (477.885 us; speedup 1.0000x reference)
//
#include <hip/hip_runtime.h>
#include <hip/hip_bf16.h>
#include <math.h>

typedef unsigned short u16;
typedef unsigned int u32;
typedef __attribute__((ext_vector_type(8))) short short8;
typedef __attribute__((ext_vector_type(8))) u16 ushort8;
typedef __attribute__((ext_vector_type(4))) float f32x4;
typedef __attribute__((ext_vector_type(16))) float f32x16;
typedef __attribute__((ext_vector_type(4))) u32 u32x4;

#define N_B 4
#define L_S 2048
#define E_D 2048
#define NH 16
#define HD 128
#define WIN 1024
#define QW 3072  // QKV buffer row width: 2048 q | 512 k | 512 v
#define LOG2E 1.4426950408889634f

static __device__ __forceinline__ u16 f32_bf16(float f) {
  u32 u = __builtin_bit_cast(u32, f);
  u = (u + 0x7fffu + ((u >> 16) & 1u)) >> 16;  // RNE
  return (u16)u;
}
static __device__ __forceinline__ float bf16_f32(u16 h) {
  u32 u = ((u32)h) << 16;
  return __builtin_bit_cast(float, u);
}
static __device__ __forceinline__ u32 pack_bf16_pair(float lo, float hi) {
  __hip_bfloat162 h2 = __float22bfloat162_rn(make_float2(lo, hi));  // RNE, .x = low
  u32 r;
  __builtin_memcpy(&r, &h2, 4);
  return r;
}
static __device__ __forceinline__ void gload_lds16(const void* g, void* l) {
  __builtin_amdgcn_global_load_lds((__attribute__((address_space(1))) void*)g,
                                   (__attribute__((address_space(3))) void*)l, 16, 0, 0);
}

// ---------------- fp32 -> bf16 cast (n multiple of 8) ----------------
__global__ void k_cast(const float* __restrict__ src, u16* __restrict__ dst, int n8) {
  int i = blockIdx.x * blockDim.x + threadIdx.x;
  if (i >= n8) return;
  const float4* s = (const float4*)src + (size_t)i * 2;
  float4 a = s[0], b = s[1];
  ushort8 v;
  v[0] = f32_bf16(a.x); v[1] = f32_bf16(a.y); v[2] = f32_bf16(a.z); v[3] = f32_bf16(a.w);
  v[4] = f32_bf16(b.x); v[5] = f32_bf16(b.y); v[6] = f32_bf16(b.z); v[7] = f32_bf16(b.w);
  *((ushort8*)dst + i) = v;
}

// ---------------- RoPE cos/sin table: [L][64] ----------------
__global__ void k_rope_table(float* __restrict__ cs, float* __restrict__ sn) {
  int idx = blockIdx.x * blockDim.x + threadIdx.x;  // 2048*64
  int l = idx >> 6, f = idx & 63;
  float freq = exp2f(-(float)f * (13.287712379549449f / 64.0f));  // 10000^(-2f/128)
  float ang = (float)l * freq;
  cs[idx] = cosf(ang);
  sn[idx] = sinf(ang);
}

// ---------------- interleaved RoPE applied in place to Q and K of QKV ----------------
__global__ void k_rope_apply(u16* __restrict__ QKV, const float* __restrict__ cs,
                             const float* __restrict__ sn) {
  int idx = blockIdx.x * blockDim.x + threadIdx.x;  // 8192*20*64 exactly
  int f = idx & 63;
  int rest = idx >> 6;
  int hh = rest % 20;          // 0..15 q heads, 16..19 kv heads
  int row = rest / 20;         // 0..8191 (= n*L + l)
  int l = row & (L_S - 1);
  int col = (hh < NH) ? (hh * HD + 2 * f) : (E_D + (hh - NH) * HD + 2 * f);
  u32* p = (u32*)(QKV + (size_t)row * QW + col);
  u32 v = *p;
  float xr = bf16_f32((u16)(v & 0xffffu));
  float xi = bf16_f32((u16)(v >> 16));
  float c = cs[l * 64 + f], s = sn[l * 64 + f];
  float orr = xr * c - xi * s;
  float oii = xr * s + xi * c;
  *p = (u32)f32_bf16(orr) | ((u32)f32_bf16(oii) << 16);
}

// ---------------- C = A @ B^T, 256x256 tile, BK=64, 4-phase fine-interleaved ----
// 8 waves (2M x 4N), per-wave C = 128x64, acc[8][4].
// LDS regions (contiguous per stage-unit, rule #21):
//   A[slot][qm*2+kk]: 8 KB = rows {qm*64+[0,64)} u {128+qm*64+[0,64)} x 32 K-cols
//   B[slot][kk]: 16 KB = all 256 n-rows x 32 K-cols         (slot = ktile & 1)
// Total 2*(4*8K) + 2*(2*16K) = 128 KB, 1 block/CU.
// Phase p of K-tile t: (qm=p&1, kk=p>>1): 2 stage gloads + 8 ds_read_b128 +
// [vmcnt(4) at p3 only] + lgkmcnt(0) + barrier + 16 MFMA.
// Region lifetime audit: A(qm,kk) read ONLY in its phase -> freed at that
// phase's barrier; B(kk) read in phases {kk*2, kk*2+1} -> freed at p1/p3.
// Stage placement (one barrier after free, >=2 phases before vmcnt-drain):
//   p0: A(1,1)@t+1, B(1,h0)@t+1   (regions freed at (t-1,p3))
//   p1: B(1,h1)@t+1, A(0,0)@t+2   (B(1) freed (t-1,p3); A(0,0) freed (t,p0))
//   p2: A(1,0)@t+2, B(0,h0)@t+2   (freed (t,p1))
//   p3: B(0,h1)@t+2, A(0,1)@t+2   (B(0) freed (t,p1); A(0,1) freed (t,p2))
// vmcnt(4) at p3 drains all units issued <= (t,p1) -> tile t+1 fully published
// before (t+1,p0) reads. Never 0 in-loop (T4). Swizzle: col_byte ^ (row&3)<<4,
// pre-applied on gload SOURCE (linear LDS dest), same XOR on ds_read (~4-way).
// XCD A-panel blocking: fid&7 = XCD chunk, 4 m-tiles/XCD (A-panel 4MB = L2).
template <int OUT_F32>
__global__ __launch_bounds__(512, 1) void k_gemm8p(
    const u16* __restrict__ A, int lda,
    const u16* __restrict__ B, int ldb,
    void* __restrict__ Cp, int ldc, int K) {
  __shared__ __align__(16) char Ab[2][4][8192];
  __shared__ __align__(16) char Bb[2][2][16384];
  const int tid = threadIdx.x;
  const int lane = tid & 63, w = tid >> 6;
  const int lr = lane & 15, lg = lane >> 4;
  const int wm = w >> 2, wn = w & 3;
  const int fid = blockIdx.x;
  const int cc = fid & 7, l = fid >> 3;
  const int m0 = (cc * 4 + (l & 3)) * 256;
  const int n0 = (l >> 2) * 256;
  const int nt = K >> 6;                      // K-tiles of 64 (K=2048 -> 32)
  const int srow = tid >> 2;                  // staging local row 0..127
  const int skey = (srow & 3) << 4;
  const int scolb = ((tid & 3) * 16) ^ skey;  // pre-swizzled source col byte
  const int rkey = (lr & 3) << 4;             // read-side XOR

  auto STAGE_A = [&](int T, int qm, int kk) {
    if (T >= nt) return;
    int g = m0 + qm * 64 + (srow & 63) + (srow >> 6) * 128;
    gload_lds16(A + (size_t)g * lda + T * 64 + kk * 32 + (scolb >> 1),
                &Ab[T & 1][qm * 2 + kk][0] + (tid << 4));
  };
  auto STAGE_B = [&](int T, int kk, int h) {
    if (T >= nt) return;
    int g = n0 + h * 128 + srow;
    gload_lds16(B + (size_t)g * ldb + T * 64 + kk * 32 + (scolb >> 1),
                &Bb[T & 1][kk][0] + h * 8192 + (tid << 4));
  };

  f32x4 acc[8][4];
  const f32x4 z4 = {0.f, 0.f, 0.f, 0.f};
#pragma unroll
  for (int mf = 0; mf < 8; ++mf)
#pragma unroll
    for (int nf = 0; nf < 4; ++nf) acc[mf][nf] = z4;

  // prologue: fully stage tiles 0 and 1 (16 loads), drain tile 0 (vmcnt(8))
#pragma unroll
  for (int T = 0; T < 2; ++T) {
    STAGE_A(T, 0, 0); STAGE_A(T, 0, 1); STAGE_A(T, 1, 0); STAGE_A(T, 1, 1);
    STAGE_B(T, 0, 0); STAGE_B(T, 0, 1); STAGE_B(T, 1, 0); STAGE_B(T, 1, 1);
  }
  asm volatile("s_waitcnt vmcnt(8)" ::: "memory");
  __builtin_amdgcn_sched_barrier(0);
  __builtin_amdgcn_s_barrier();
  __builtin_amdgcn_sched_barrier(0);

  for (int t = 0; t < nt; ++t) {
    const int s = t & 1;
#pragma unroll
    for (int p = 0; p < 4; ++p) {
      const int qm = p & 1, kk = p >> 1;
      // --- stage 2 units (schedule in header comment) ---
      if (p == 0)      { STAGE_A(t + 1, 1, 1); STAGE_B(t + 1, 1, 0); }
      else if (p == 1) { STAGE_B(t + 1, 1, 1); STAGE_A(t + 2, 0, 0); }
      else if (p == 2) { STAGE_A(t + 2, 1, 0); STAGE_B(t + 2, 0, 0); }
      else             { STAGE_B(t + 2, 0, 1); STAGE_A(t + 2, 0, 1); }
      // --- 8 ds_read_b128 for this phase's quadrant ---
      short8 af[4], bf[4];
#pragma unroll
      for (int mf = 0; mf < 4; ++mf) {
        int row = wm * 64 + mf * 16 + lr;
        af[mf] = *(const short8*)(&Ab[s][qm * 2 + kk][0] + row * 64 + ((lg * 16) ^ rkey));
      }
#pragma unroll
      for (int nf = 0; nf < 4; ++nf) {
        int row = wn * 64 + nf * 16 + lr;
        bf[nf] = *(const short8*)(&Bb[s][kk][0] + row * 64 + ((lg * 16) ^ rkey));
      }
      if (p == 3)
        asm volatile("s_waitcnt vmcnt(4) lgkmcnt(0)" ::: "memory");
      else
        asm volatile("s_waitcnt lgkmcnt(0)" ::: "memory");
      __builtin_amdgcn_sched_barrier(0);
      __builtin_amdgcn_s_barrier();
      __builtin_amdgcn_sched_barrier(0);
      // --- 16 MFMA (register-only; overlaps other waves' next-phase loads) ---
      __builtin_amdgcn_s_setprio(1);
#pragma unroll
      for (int mf = 0; mf < 4; ++mf)
#pragma unroll
        for (int nf = 0; nf < 4; ++nf)
          acc[qm * 4 + mf][nf] =
              __builtin_amdgcn_mfma_f32_16x16x32_bf16(af[mf], bf[nf], acc[qm * 4 + mf][nf], 0, 0, 0);
      __builtin_amdgcn_s_setprio(0);
    }
  }

#pragma unroll
  for (int mf = 0; mf < 8; ++mf)
#pragma unroll
    for (int nf = 0; nf < 4; ++nf)
#pragma unroll
      for (int j = 0; j < 4; ++j) {
        size_t r = (size_t)(m0 + wm * 128 + mf * 16 + lg * 4 + j);
        int c = n0 + wn * 64 + nf * 16 + lr;
        if (OUT_F32)
          ((float*)Cp)[r * ldc + c] = acc[mf][nf][j];
        else
          ((u16*)Cp)[r * ldc + c] = f32_bf16(acc[mf][nf][j]);
      }
}

// ---------------- sliding-window flash attention (pipelined, 8 waves, 32x32 MFMA) ----
// (unchanged from round 15/16 — passing)
__global__ __launch_bounds__(512, 2) void k_attn(u16* __restrict__ QKV) {
  const int bx = blockIdx.x, h = blockIdx.y, b = blockIdx.z;
  const int qb = (b >= 2) ? 7 - bx : bx;        // cost-balanced remap
  const int tid = threadIdx.x;
  const int lane = tid & 63, w = tid >> 6;      // 8 waves
  const int l31 = lane & 31, hi = lane >> 5;
  const int kh = h >> 2;
  const int qs = qb * 256 + w * 32;
  __shared__ __align__(16) u16 Klds[2][64 * 128];  // [kv][d], swizzled, 2 buffers
  __shared__ __align__(16) u16 Vt[2][128 * 64];    // [d][kv], swizzled, 2 buffers
  const float SCL2 = 0.08838834764831845f * 1.4426950408889634f;  // scale*log2(e)
  const size_t bL = (size_t)b * L_S;
  const int q = qs + l31;
  const size_t rowQ = (bL + q) * QW + h * HD;
  short8 qf[8];
#pragma unroll
  for (int ds = 0; ds < 8; ++ds)
    qf[ds] = *(const short8*)(QKV + rowQ + ds * 16 + hi * 8);
  f32x16 o[4];
#pragma unroll
  for (int dt = 0; dt < 4; ++dt)
#pragma unroll
    for (int r = 0; r < 16; ++r) o[dt][r] = 0.f;
  float m2 = -3e38f, lsum = 0.f;  // per-lane stats for this lane's q (log2 domain)
  int t0 = qb * 256 - (WIN - 1);
  if (t0 < 0) t0 = 0;
  t0 >>= 6;
  const int t1 = 4 * qb + 3;  // == (qb*256+255)>>6
  short8 vreg[2];

  auto ISSUE_K = [&](int t, int buf) {
    char* Kb = (char*)Klds + buf * 16384;
#pragma unroll
    for (int rr = 0; rr < 2; ++rr) {
      int row = rr * 32 + (tid >> 4);              // 0..63
      int colb = ((tid & 15) * 16) ^ ((row & 7) << 4);  // inverse-swizzled source
      gload_lds16(QKV + (bL + t * 64 + row) * QW + E_D + kh * HD + (colb >> 1),
                  Kb + rr * 8192 + w * 1024 + (lane << 4));
    }
  };
  auto LOAD_V = [&](int t) {
#pragma unroll
    for (int rr = 0; rr < 2; ++rr)
      vreg[rr] = *(const short8*)(QKV + (bL + t * 64 + lane) * QW + E_D + 512 + kh * HD +
                                  ((w * 2 + rr) * 8));
  };
  auto WRITE_V = [&](int buf) {
    char* Vb = (char*)Vt + buf * 16384;
#pragma unroll
    for (int rr = 0; rr < 2; ++rr) {
      int db = (w * 2 + rr) * 8;                   // multiple of 8 -> row&7 == e
#pragma unroll
      for (int e = 0; e < 8; ++e)
        *(u16*)(Vb + ((((db + e) * 128) + lane * 2) ^ (e << 4))) = (u16)vreg[rr][e];
    }
  };

  LOAD_V(t0);
  ISSUE_K(t0, 0);
  __syncthreads();          // drains K gloads + V reg loads
  WRITE_V(0);               // Vt[0] = V(t0); published by barrier1 of iter t0
  int c = 0;

  for (int t = t0; t <= t1; ++t) {
    const int kv0 = t * 64;
    const int tn = (t < t1) ? t + 1 : t1;
    ISSUE_K(tn, c ^ 1);
    LOAD_V(tn);
    const bool act = (kv0 <= qs + 31) && (kv0 + 63 > qs - WIN);
    u32x4 pa[4];  // assembled PV A-frags (bf16 x8 each)
    if (act) {
      char* Kb = (char*)Klds + c * 16384;
      f32x16 s[2];
#pragma unroll
      for (int g = 0; g < 2; ++g)
#pragma unroll
        for (int r = 0; r < 16; ++r) s[g][r] = 0.f;
#pragma unroll
      for (int g = 0; g < 2; ++g) {
        const int r = g * 32 + l31;                  // K row this lane reads
        const int rsw = (r & 7) << 4;
#pragma unroll
        for (int ds = 0; ds < 8; ++ds) {
          short8 kf = *(const short8*)(Kb + (r * 256 + ((ds * 32 + hi * 16) ^ rsw)));
          s[g] = __builtin_amdgcn_mfma_f32_32x32x16_bf16(kf, qf[ds], s[g], 0, 0, 0);
        }
      }
      float v[2][16];
      float mx = -3e38f;
#pragma unroll
      for (int g = 0; g < 2; ++g)
#pragma unroll
        for (int r = 0; r < 16; ++r) {
          int kg = kv0 + g * 32 + (r & 3) + 8 * (r >> 2) + 4 * hi;
          bool a = (kg <= q) && (kg > q - WIN);
          float vv = a ? s[g][r] * SCL2 : -3e38f;
          v[g][r] = vv;
          mx = fmaxf(mx, vv);
        }
      mx = fmaxf(mx, __shfl_xor(mx, 32));            // partner has other kv half
      if (__ballot(mx > m2 + 11.5415603f)) {
        float mn = fmaxf(m2, mx);
        float alpha = exp2f(m2 - mn);
        m2 = mn;
        lsum *= alpha;
#pragma unroll
        for (int r = 0; r < 16; ++r) {
          float alr = __shfl(alpha, (r & 3) + 8 * (r >> 2) + 4 * hi);
#pragma unroll
          for (int dt = 0; dt < 4; ++dt) o[dt][r] *= alr;
        }
      }
      float rs = 0.f;
#pragma unroll
      for (int g = 0; g < 2; ++g)
#pragma unroll
        for (int r = 0; r < 16; ++r) {
          float pe = (v[g][r] > -1e37f) ? exp2f(v[g][r] - m2) : 0.f;
          v[g][r] = pe;
          rs += pe;
        }
      rs += __shfl_xor(rs, 32);
      lsum += rs;
#pragma unroll
      for (int g = 0; g < 2; ++g) {
        u32 W[8];
#pragma unroll
        for (int qi = 0; qi < 4; ++qi) {
          W[2 * qi]     = pack_bf16_pair(v[g][4 * qi + 0], v[g][4 * qi + 1]);
          W[2 * qi + 1] = pack_bf16_pair(v[g][4 * qi + 2], v[g][4 * qi + 3]);
        }
        u32 R[4];
        R[0] = __shfl_xor(hi ? W[0] : W[2], 32);
        R[1] = __shfl_xor(hi ? W[1] : W[3], 32);
        R[2] = __shfl_xor(hi ? W[4] : W[6], 32);
        R[3] = __shfl_xor(hi ? W[5] : W[7], 32);
#pragma unroll
        for (int ksl = 0; ksl < 2; ++ksl) {
          u32x4 fr;
          if (hi == 0) {
            fr[0] = W[4 * ksl]; fr[1] = W[4 * ksl + 1];
            fr[2] = R[2 * ksl]; fr[3] = R[2 * ksl + 1];
          } else {
            fr[0] = R[2 * ksl]; fr[1] = R[2 * ksl + 1];
            fr[2] = W[4 * ksl + 2]; fr[3] = W[4 * ksl + 3];
          }
          pa[g * 2 + ksl] = fr;
        }
      }
    }
    __syncthreads();  // barrier1: drains K(tn)+V(tn) loads; publishes Vt[c]; orders reuse
    WRITE_V(c ^ 1);   // stage V(tn) into spare buffer (PV below reads Vt[c])
    if (act) {
      char* Vb = (char*)Vt + c * 16384;
      __builtin_amdgcn_s_setprio(1);
#pragma unroll
      for (int dt = 0; dt < 4; ++dt) {
        const int d = dt * 32 + l31;
        const int dsw = (d & 7) << 4;
#pragma unroll
        for (int ks = 0; ks < 4; ++ks) {
          short8 vf = *(const short8*)(Vb + (d * 128 + ((ks * 32 + hi * 16) ^ dsw)));
          o[dt] = __builtin_amdgcn_mfma_f32_32x32x16_bf16(
              __builtin_bit_cast(short8, pa[ks]), vf, o[dt], 0, 0, 0);
        }
      }
      __builtin_amdgcn_s_setprio(0);
    }
    c ^= 1;
  }
  float inv = 1.0f / lsum;
#pragma unroll
  for (int r = 0; r < 16; ++r) {
    int ridx = (r & 3) + 8 * (r >> 2) + 4 * hi;
    float invr = __shfl(inv, ridx);
    size_t rowO = (bL + qs + ridx) * QW + h * HD + l31;
#pragma unroll
    for (int dt = 0; dt < 4; ++dt)
      QKV[rowO + dt * 32] = f32_bf16(o[dt][r] * invr);
  }
}

extern "C" void kernel_launch(void* const* d_in, const int* in_sizes, int n_in,
                              void* d_out, int out_size, void* d_ws, size_t ws_size,
                              hipStream_t stream) {
  const float* x  = (const float*)d_in[0];
  const float* Wq = (const float*)d_in[1];
  const float* Wk = (const float*)d_in[2];
  const float* Wv = (const float*)d_in[3];
  const float* Wo = (const float*)d_in[4];
  char* ws = (char*)d_ws;
  // Workspace layout (total 105,906,176 B). If the harness workspace is too
  // small, bail out cleanly (validation fails loudly instead of GPU faulting).
  if (ws_size < 105906176u) return;
  u16* xb    = (u16*)(ws);                    // 8192*2048*2 = 33554432
  u16* Wqkv  = (u16*)(ws + 33554432);         // 3072*2048*2 = 12582912
  u16* Wob   = (u16*)(ws + 46137344);         // 2048*2048*2 =  8388608
  u16* QKV   = (u16*)(ws + 54525952);         // 8192*3072*2 = 50331648
  float* cs  = (float*)(ws + 104857600);      // 131072*4    =   524288
  float* sn  = (float*)(ws + 105381888);      // total end 105906176 B

  // bf16 casts (weights packed: Wq rows 0..2047 | Wk rows 2048..2559 | Wv rows 2560..3071)
  k_cast<<<8192, 256, 0, stream>>>(x, xb, 16777216 / 8);
  k_cast<<<2048, 256, 0, stream>>>(Wq, Wqkv, 4194304 / 8);
  k_cast<<<512, 256, 0, stream>>>(Wk, Wqkv + 2048 * 2048, 1048576 / 8);
  k_cast<<<512, 256, 0, stream>>>(Wv, Wqkv + 2560 * 2048, 1048576 / 8);
  k_cast<<<2048, 256, 0, stream>>>(Wo, Wob, 4194304 / 8);
  k_rope_table<<<512, 256, 0, stream>>>(cs, sn);
  // fused QKV projection: [Q|K|V] = xb @ Wqkv^T  (256^2 tiles: 32 m x 12 n = 384 wg)
  k_gemm8p<0><<<384, 512, 0, stream>>>(xb, 2048, Wqkv, 2048, QKV, QW, 2048);
  // RoPE in place on Q and K regions
  k_rope_apply<<<40960, 256, 0, stream>>>(QKV, cs, sn);
  // flash attention; Z overwrites Q region of QKV
  k_attn<<<dim3(8, 16, 4), 512, 0, stream>>>(QKV);
  // out = Z @ Wo^T (fp32 out; 32 m x 8 n = 256 wg)
  k_gemm8p<1><<<256, 512, 0, stream>>>(QKV, QW, Wob, 2048, d_out, 2048, 2048);
}

// Round 18
// 458.557 us; speedup vs baseline: 1.0422x; 1.0422x over previous
//
#include <hip/hip_runtime.h>
#include <hip/hip_bf16.h>
#include <math.h>

typedef unsigned short u16;
typedef unsigned int u32;
typedef __attribute__((ext_vector_type(8))) short short8;
typedef __attribute__((ext_vector_type(8))) u16 ushort8;
typedef __attribute__((ext_vector_type(4))) float f32x4;
typedef __attribute__((ext_vector_type(16))) float f32x16;
typedef __attribute__((ext_vector_type(4))) u32 u32x4;

#define N_B 4
#define L_S 2048
#define E_D 2048
#define NH 16
#define HD 128
#define WIN 1024
#define QW 3072  // QKV buffer row width: 2048 q | 512 k | 512 v
#define LOG2E 1.4426950408889634f

static __device__ __forceinline__ u16 f32_bf16(float f) {
  u32 u = __builtin_bit_cast(u32, f);
  u = (u + 0x7fffu + ((u >> 16) & 1u)) >> 16;  // RNE
  return (u16)u;
}
static __device__ __forceinline__ float bf16_f32(u16 h) {
  u32 u = ((u32)h) << 16;
  return __builtin_bit_cast(float, u);
}
static __device__ __forceinline__ u32 pack_bf16_pair(float lo, float hi) {
  __hip_bfloat162 h2 = __float22bfloat162_rn(make_float2(lo, hi));  // RNE, .x = low
  u32 r;
  __builtin_memcpy(&r, &h2, 4);
  return r;
}
static __device__ __forceinline__ void gload_lds16(const void* g, void* l) {
  __builtin_amdgcn_global_load_lds((__attribute__((address_space(1))) void*)g,
                                   (__attribute__((address_space(3))) void*)l, 16, 0, 0);
}

// ---------------- fp32 -> bf16 cast (n multiple of 8) ----------------
__global__ void k_cast(const float* __restrict__ src, u16* __restrict__ dst, int n8) {
  int i = blockIdx.x * blockDim.x + threadIdx.x;
  if (i >= n8) return;
  const float4* s = (const float4*)src + (size_t)i * 2;
  float4 a = s[0], b = s[1];
  ushort8 v;
  v[0] = f32_bf16(a.x); v[1] = f32_bf16(a.y); v[2] = f32_bf16(a.z); v[3] = f32_bf16(a.w);
  v[4] = f32_bf16(b.x); v[5] = f32_bf16(b.y); v[6] = f32_bf16(b.z); v[7] = f32_bf16(b.w);
  *((ushort8*)dst + i) = v;
}

// ---------------- RoPE cos/sin table: [L][64] ----------------
__global__ void k_rope_table(float* __restrict__ cs, float* __restrict__ sn) {
  int idx = blockIdx.x * blockDim.x + threadIdx.x;  // 2048*64
  int l = idx >> 6, f = idx & 63;
  float freq = exp2f(-(float)f * (13.287712379549449f / 64.0f));  // 10000^(-2f/128)
  float ang = (float)l * freq;
  cs[idx] = cosf(ang);
  sn[idx] = sinf(ang);
}

// ---------------- C = A @ B^T, 256x256 tile, BK=32, 3-buf counted-vmcnt pipeline ----
// (body identical to round 16 — best passing GEMM: 0 bank conflicts, FETCH 82MB)
// NEW: ROPE template flag — fused interleaved RoPE in the epilogue for the QKV
// GEMM. Col pairs (2f,2f+1) sit in adjacent lanes (lr, lr^1): partner via
// __shfl_xor(v,1); even lane: v*cos - px*sin; odd lane: px*sin + v*cos.
// Applied only to cols < 2560 (Q|K regions; frag-uniform predicate). RoPE on
// fp32 acc BEFORE bf16 rounding (better accuracy than the old in-place pass).
template <int OUT_F32, int ROPE>
__global__ __launch_bounds__(512, 1) void k_gemm256(
    const u16* __restrict__ A, int lda,
    const u16* __restrict__ B, int ldb,
    void* __restrict__ Cp, int ldc, int K,
    const float* __restrict__ cs, const float* __restrict__ sn) {
  __shared__ __align__(16) u16 Ab[3 * 8192];  // 3 x [256][32]
  __shared__ __align__(16) u16 Bb[3 * 8192];
  const int tid = threadIdx.x;
  const int lane = tid & 63, w = tid >> 6;
  const int lr = lane & 15, lg = lane >> 4;
  const int wm = w >> 2, wn = w & 3;
  const int fid = blockIdx.x;
  const int cc = fid & 7, l = fid >> 3;
  const int m0 = (cc * 4 + (l & 3)) * 256;
  const int n0 = (l >> 2) * 256;
  const int rswz = (lr & 6) << 3;  // read-side XOR (row bits 1-2)

  auto STAGE = [&](int kt, int bb) {
    const int r2 = tid >> 2;                               // 0..127
    const int ce = (((tid & 3) * 16) ^ ((r2 & 6) << 3)) >> 1;  // pre-swizzled src col (elems)
#pragma unroll
    for (int rr = 0; rr < 2; ++rr) {
      int row = rr * 128 + r2;
      gload_lds16(A + (size_t)(m0 + row) * lda + kt * 32 + ce,
                  (char*)Ab + bb * 16384 + rr * 8192 + (w << 10));
      gload_lds16(B + (size_t)(n0 + row) * ldb + kt * 32 + ce,
                  (char*)Bb + bb * 16384 + rr * 8192 + (w << 10));
    }
  };

  f32x4 acc[8][4];
  const f32x4 z4 = {0.f, 0.f, 0.f, 0.f};
#pragma unroll
  for (int mf = 0; mf < 8; ++mf)
#pragma unroll
    for (int nf = 0; nf < 4; ++nf) acc[mf][nf] = z4;

  const int nt = K >> 5;  // K-tiles of 32 (K=2048 -> 64; requires nt >= 3)
  STAGE(0, 0);
  STAGE(1, 1);
  asm volatile("s_waitcnt vmcnt(4)" ::: "memory");  // tile0's 4 loads done; tile1 in flight
  __builtin_amdgcn_sched_barrier(0);
  __builtin_amdgcn_s_barrier();
  __builtin_amdgcn_sched_barrier(0);

  int c3 = 0;
  for (int t = 0; t < nt; ++t) {
    int ib = c3 + 2; if (ib >= 3) ib -= 3;
    if (t + 2 < nt) STAGE(t + 2, ib);
    const char* Abt = (const char*)Ab + c3 * 16384;
    const char* Bbt = (const char*)Bb + c3 * 16384;
    short8 af[8], bf[4];
#pragma unroll
    for (int nf = 0; nf < 4; ++nf) {
      int row = wn * 64 + nf * 16 + lr;
      bf[nf] = *(const short8*)(Bbt + row * 64 + ((lg * 16) ^ rswz));
    }
#pragma unroll
    for (int mf = 0; mf < 8; ++mf) {
      int row = wm * 128 + mf * 16 + lr;
      af[mf] = *(const short8*)(Abt + row * 64 + ((lg * 16) ^ rswz));
    }
    __builtin_amdgcn_s_setprio(1);
#pragma unroll
    for (int mf = 0; mf < 8; ++mf)
#pragma unroll
      for (int nf = 0; nf < 4; ++nf)
        acc[mf][nf] =
            __builtin_amdgcn_mfma_f32_16x16x32_bf16(af[mf], bf[nf], acc[mf][nf], 0, 0, 0);
    __builtin_amdgcn_s_setprio(0);
    // publish tile t+1 (issued at iter t-1); keep tile t+2's 4 loads in flight
    if (t + 2 < nt)
      asm volatile("s_waitcnt vmcnt(4) lgkmcnt(0)" ::: "memory");
    else
      asm volatile("s_waitcnt vmcnt(0) lgkmcnt(0)" ::: "memory");
    __builtin_amdgcn_sched_barrier(0);
    __builtin_amdgcn_s_barrier();
    __builtin_amdgcn_sched_barrier(0);
    c3 = (c3 == 2) ? 0 : c3 + 1;
  }

#pragma unroll
  for (int mf = 0; mf < 8; ++mf) {
    const int rbase = m0 + wm * 128 + mf * 16 + lg * 4;
#pragma unroll
    for (int j = 0; j < 4; ++j) {
      const int lrow = (rbase + j) & (L_S - 1);
      const float* csl = ROPE ? (cs + lrow * 64) : nullptr;
      const float* snl = ROPE ? (sn + lrow * 64) : nullptr;
#pragma unroll
      for (int nf = 0; nf < 4; ++nf) {
        float v = acc[mf][nf][j];
        const int c0 = n0 + wn * 64 + nf * 16;     // frag col base (16-aligned)
        if (ROPE && c0 < 2560) {                   // Q|K region, frag-uniform
          float px = __shfl_xor(v, 1);             // partner col (lr^1)
          int f = ((c0 + lr) & 127) >> 1;          // head-dim pair index
          float co = csl[f], si = snl[f];
          v = (lr & 1) ? (px * si + v * co) : (v * co - px * si);
        }
        size_t r = (size_t)(rbase + j);
        int c = c0 + lr;
        if (OUT_F32)
          ((float*)Cp)[r * ldc + c] = v;
        else
          ((u16*)Cp)[r * ldc + c] = f32_bf16(v);
      }
    }
  }
}

// ---------------- sliding-window flash attention (pipelined, 8 waves, 32x32 MFMA) ----
// (unchanged from rounds 15-17 — passing)
__global__ __launch_bounds__(512, 2) void k_attn(u16* __restrict__ QKV) {
  const int bx = blockIdx.x, h = blockIdx.y, b = blockIdx.z;
  const int qb = (b >= 2) ? 7 - bx : bx;        // cost-balanced remap
  const int tid = threadIdx.x;
  const int lane = tid & 63, w = tid >> 6;      // 8 waves
  const int l31 = lane & 31, hi = lane >> 5;
  const int kh = h >> 2;
  const int qs = qb * 256 + w * 32;
  __shared__ __align__(16) u16 Klds[2][64 * 128];  // [kv][d], swizzled, 2 buffers
  __shared__ __align__(16) u16 Vt[2][128 * 64];    // [d][kv], swizzled, 2 buffers
  const float SCL2 = 0.08838834764831845f * 1.4426950408889634f;  // scale*log2(e)
  const size_t bL = (size_t)b * L_S;
  const int q = qs + l31;
  const size_t rowQ = (bL + q) * QW + h * HD;
  short8 qf[8];
#pragma unroll
  for (int ds = 0; ds < 8; ++ds)
    qf[ds] = *(const short8*)(QKV + rowQ + ds * 16 + hi * 8);
  f32x16 o[4];
#pragma unroll
  for (int dt = 0; dt < 4; ++dt)
#pragma unroll
    for (int r = 0; r < 16; ++r) o[dt][r] = 0.f;
  float m2 = -3e38f, lsum = 0.f;  // per-lane stats for this lane's q (log2 domain)
  int t0 = qb * 256 - (WIN - 1);
  if (t0 < 0) t0 = 0;
  t0 >>= 6;
  const int t1 = 4 * qb + 3;  // == (qb*256+255)>>6
  short8 vreg[2];

  auto ISSUE_K = [&](int t, int buf) {
    char* Kb = (char*)Klds + buf * 16384;
#pragma unroll
    for (int rr = 0; rr < 2; ++rr) {
      int row = rr * 32 + (tid >> 4);              // 0..63
      int colb = ((tid & 15) * 16) ^ ((row & 7) << 4);  // inverse-swizzled source
      gload_lds16(QKV + (bL + t * 64 + row) * QW + E_D + kh * HD + (colb >> 1),
                  Kb + rr * 8192 + w * 1024 + (lane << 4));
    }
  };
  auto LOAD_V = [&](int t) {
#pragma unroll
    for (int rr = 0; rr < 2; ++rr)
      vreg[rr] = *(const short8*)(QKV + (bL + t * 64 + lane) * QW + E_D + 512 + kh * HD +
                                  ((w * 2 + rr) * 8));
  };
  auto WRITE_V = [&](int buf) {
    char* Vb = (char*)Vt + buf * 16384;
#pragma unroll
    for (int rr = 0; rr < 2; ++rr) {
      int db = (w * 2 + rr) * 8;                   // multiple of 8 -> row&7 == e
#pragma unroll
      for (int e = 0; e < 8; ++e)
        *(u16*)(Vb + ((((db + e) * 128) + lane * 2) ^ (e << 4))) = (u16)vreg[rr][e];
    }
  };

  LOAD_V(t0);
  ISSUE_K(t0, 0);
  __syncthreads();          // drains K gloads + V reg loads
  WRITE_V(0);               // Vt[0] = V(t0); published by barrier1 of iter t0
  int c = 0;

  for (int t = t0; t <= t1; ++t) {
    const int kv0 = t * 64;
    const int tn = (t < t1) ? t + 1 : t1;
    ISSUE_K(tn, c ^ 1);
    LOAD_V(tn);
    const bool act = (kv0 <= qs + 31) && (kv0 + 63 > qs - WIN);
    u32x4 pa[4];  // assembled PV A-frags (bf16 x8 each)
    if (act) {
      char* Kb = (char*)Klds + c * 16384;
      f32x16 s[2];
#pragma unroll
      for (int g = 0; g < 2; ++g)
#pragma unroll
        for (int r = 0; r < 16; ++r) s[g][r] = 0.f;
#pragma unroll
      for (int g = 0; g < 2; ++g) {
        const int r = g * 32 + l31;                  // K row this lane reads
        const int rsw = (r & 7) << 4;
#pragma unroll
        for (int ds = 0; ds < 8; ++ds) {
          short8 kf = *(const short8*)(Kb + (r * 256 + ((ds * 32 + hi * 16) ^ rsw)));
          s[g] = __builtin_amdgcn_mfma_f32_32x32x16_bf16(kf, qf[ds], s[g], 0, 0, 0);
        }
      }
      float v[2][16];
      float mx = -3e38f;
#pragma unroll
      for (int g = 0; g < 2; ++g)
#pragma unroll
        for (int r = 0; r < 16; ++r) {
          int kg = kv0 + g * 32 + (r & 3) + 8 * (r >> 2) + 4 * hi;
          bool a = (kg <= q) && (kg > q - WIN);
          float vv = a ? s[g][r] * SCL2 : -3e38f;
          v[g][r] = vv;
          mx = fmaxf(mx, vv);
        }
      mx = fmaxf(mx, __shfl_xor(mx, 32));            // partner has other kv half
      if (__ballot(mx > m2 + 11.5415603f)) {
        float mn = fmaxf(m2, mx);
        float alpha = exp2f(m2 - mn);
        m2 = mn;
        lsum *= alpha;
#pragma unroll
        for (int r = 0; r < 16; ++r) {
          float alr = __shfl(alpha, (r & 3) + 8 * (r >> 2) + 4 * hi);
#pragma unroll
          for (int dt = 0; dt < 4; ++dt) o[dt][r] *= alr;
        }
      }
      float rs = 0.f;
#pragma unroll
      for (int g = 0; g < 2; ++g)
#pragma unroll
        for (int r = 0; r < 16; ++r) {
          float pe = (v[g][r] > -1e37f) ? exp2f(v[g][r] - m2) : 0.f;
          v[g][r] = pe;
          rs += pe;
        }
      rs += __shfl_xor(rs, 32);
      lsum += rs;
#pragma unroll
      for (int g = 0; g < 2; ++g) {
        u32 W[8];
#pragma unroll
        for (int qi = 0; qi < 4; ++qi) {
          W[2 * qi]     = pack_bf16_pair(v[g][4 * qi + 0], v[g][4 * qi + 1]);
          W[2 * qi + 1] = pack_bf16_pair(v[g][4 * qi + 2], v[g][4 * qi + 3]);
        }
        u32 R[4];
        R[0] = __shfl_xor(hi ? W[0] : W[2], 32);
        R[1] = __shfl_xor(hi ? W[1] : W[3], 32);
        R[2] = __shfl_xor(hi ? W[4] : W[6], 32);
        R[3] = __shfl_xor(hi ? W[5] : W[7], 32);
#pragma unroll
        for (int ksl = 0; ksl < 2; ++ksl) {
          u32x4 fr;
          if (hi == 0) {
            fr[0] = W[4 * ksl]; fr[1] = W[4 * ksl + 1];
            fr[2] = R[2 * ksl]; fr[3] = R[2 * ksl + 1];
          } else {
            fr[0] = R[2 * ksl]; fr[1] = R[2 * ksl + 1];
            fr[2] = W[4 * ksl + 2]; fr[3] = W[4 * ksl + 3];
          }
          pa[g * 2 + ksl] = fr;
        }
      }
    }
    __syncthreads();  // barrier1: drains K(tn)+V(tn) loads; publishes Vt[c]; orders reuse
    WRITE_V(c ^ 1);   // stage V(tn) into spare buffer (PV below reads Vt[c])
    if (act) {
      char* Vb = (char*)Vt + c * 16384;
      __builtin_amdgcn_s_setprio(1);
#pragma unroll
      for (int dt = 0; dt < 4; ++dt) {
        const int d = dt * 32 + l31;
        const int dsw = (d & 7) << 4;
#pragma unroll
        for (int ks = 0; ks < 4; ++ks) {
          short8 vf = *(const short8*)(Vb + (d * 128 + ((ks * 32 + hi * 16) ^ dsw)));
          o[dt] = __builtin_amdgcn_mfma_f32_32x32x16_bf16(
              __builtin_bit_cast(short8, pa[ks]), vf, o[dt], 0, 0, 0);
        }
      }
      __builtin_amdgcn_s_setprio(0);
    }
    c ^= 1;
  }
  float inv = 1.0f / lsum;
#pragma unroll
  for (int r = 0; r < 16; ++r) {
    int ridx = (r & 3) + 8 * (r >> 2) + 4 * hi;
    float invr = __shfl(inv, ridx);
    size_t rowO = (bL + qs + ridx) * QW + h * HD + l31;
#pragma unroll
    for (int dt = 0; dt < 4; ++dt)
      QKV[rowO + dt * 32] = f32_bf16(o[dt][r] * invr);
  }
}

extern "C" void kernel_launch(void* const* d_in, const int* in_sizes, int n_in,
                              void* d_out, int out_size, void* d_ws, size_t ws_size,
                              hipStream_t stream) {
  const float* x  = (const float*)d_in[0];
  const float* Wq = (const float*)d_in[1];
  const float* Wk = (const float*)d_in[2];
  const float* Wv = (const float*)d_in[3];
  const float* Wo = (const float*)d_in[4];
  char* ws = (char*)d_ws;
  // Workspace layout (total 105,906,176 B). If the harness workspace is too
  // small, bail out cleanly (validation fails loudly instead of GPU faulting).
  if (ws_size < 105906176u) return;
  u16* xb    = (u16*)(ws);                    // 8192*2048*2 = 33554432
  u16* Wqkv  = (u16*)(ws + 33554432);         // 3072*2048*2 = 12582912
  u16* Wob   = (u16*)(ws + 46137344);         // 2048*2048*2 =  8388608
  u16* QKV   = (u16*)(ws + 54525952);         // 8192*3072*2 = 50331648
  float* cs  = (float*)(ws + 104857600);      // 131072*4    =   524288
  float* sn  = (float*)(ws + 105381888);      // total end 105906176 B

  // bf16 casts (weights packed: Wq rows 0..2047 | Wk rows 2048..2559 | Wv rows 2560..3071)
  k_cast<<<8192, 256, 0, stream>>>(x, xb, 16777216 / 8);
  k_cast<<<2048, 256, 0, stream>>>(Wq, Wqkv, 4194304 / 8);
  k_cast<<<512, 256, 0, stream>>>(Wk, Wqkv + 2048 * 2048, 1048576 / 8);
  k_cast<<<512, 256, 0, stream>>>(Wv, Wqkv + 2560 * 2048, 1048576 / 8);
  k_cast<<<2048, 256, 0, stream>>>(Wo, Wob, 4194304 / 8);
  k_rope_table<<<512, 256, 0, stream>>>(cs, sn);
  // fused QKV projection + RoPE: [Q|K|V] = xb @ Wqkv^T, rope on cols<2560
  k_gemm256<0, 1><<<384, 512, 0, stream>>>(xb, 2048, Wqkv, 2048, QKV, QW, 2048, cs, sn);
  // flash attention; Z overwrites Q region of QKV
  k_attn<<<dim3(8, 16, 4), 512, 0, stream>>>(QKV);
  // out = Z @ Wo^T (fp32 out; 32 m x 8 n = 256 wg)
  k_gemm256<1, 0><<<256, 512, 0, stream>>>(QKV, QW, Wob, 2048, d_out, 2048, 2048,
                                           nullptr, nullptr);
}

// Round 19
// 393.147 us; speedup vs baseline: 1.2155x; 1.1664x over previous
//
#include <hip/hip_runtime.h>
#include <hip/hip_bf16.h>
#include <math.h>

typedef unsigned short u16;
typedef unsigned int u32;
typedef __attribute__((ext_vector_type(8))) short short8;
typedef __attribute__((ext_vector_type(8))) u16 ushort8;
typedef __attribute__((ext_vector_type(4))) float f32x4;
typedef __attribute__((ext_vector_type(16))) float f32x16;
typedef __attribute__((ext_vector_type(4))) u32 u32x4;

#define N_B 4
#define L_S 2048
#define E_D 2048
#define NH 16
#define HD 128
#define WIN 1024
#define QW 3072  // QKV buffer row width: 2048 q | 512 k | 512 v
#define LOG2E 1.4426950408889634f

static __device__ __forceinline__ u16 f32_bf16(float f) {
  u32 u = __builtin_bit_cast(u32, f);
  u = (u + 0x7fffu + ((u >> 16) & 1u)) >> 16;  // RNE
  return (u16)u;
}
static __device__ __forceinline__ float bf16_f32(u16 h) {
  u32 u = ((u32)h) << 16;
  return __builtin_bit_cast(float, u);
}
static __device__ __forceinline__ u32 pack_bf16_pair(float lo, float hi) {
  __hip_bfloat162 h2 = __float22bfloat162_rn(make_float2(lo, hi));  // RNE, .x = low
  u32 r;
  __builtin_memcpy(&r, &h2, 4);
  return r;
}
static __device__ __forceinline__ void gload_lds16(const void* g, void* l) {
  __builtin_amdgcn_global_load_lds((__attribute__((address_space(1))) void*)g,
                                   (__attribute__((address_space(3))) void*)l, 16, 0, 0);
}

// ---------------- fp32 -> bf16 cast (n multiple of 8) ----------------
__global__ void k_cast(const float* __restrict__ src, u16* __restrict__ dst, int n8) {
  int i = blockIdx.x * blockDim.x + threadIdx.x;
  if (i >= n8) return;
  const float4* s = (const float4*)src + (size_t)i * 2;
  float4 a = s[0], b = s[1];
  ushort8 v;
  v[0] = f32_bf16(a.x); v[1] = f32_bf16(a.y); v[2] = f32_bf16(a.z); v[3] = f32_bf16(a.w);
  v[4] = f32_bf16(b.x); v[5] = f32_bf16(b.y); v[6] = f32_bf16(b.z); v[7] = f32_bf16(b.w);
  *((ushort8*)dst + i) = v;
}

// ---------------- RoPE cos/sin table: [L][64] ----------------
__global__ void k_rope_table(float* __restrict__ cs, float* __restrict__ sn) {
  int idx = blockIdx.x * blockDim.x + threadIdx.x;  // 2048*64
  int l = idx >> 6, f = idx & 63;
  float freq = exp2f(-(float)f * (13.287712379549449f / 64.0f));  // 10000^(-2f/128)
  float ang = (float)l * freq;
  cs[idx] = cosf(ang);
  sn[idx] = sinf(ang);
}

// ---------------- interleaved RoPE applied in place to Q and K of QKV ----------------
__global__ void k_rope_apply(u16* __restrict__ QKV, const float* __restrict__ cs,
                             const float* __restrict__ sn) {
  int idx = blockIdx.x * blockDim.x + threadIdx.x;  // 8192*20*64 exactly
  int f = idx & 63;
  int rest = idx >> 6;
  int hh = rest % 20;          // 0..15 q heads, 16..19 kv heads
  int row = rest / 20;         // 0..8191 (= n*L + l)
  int l = row & (L_S - 1);
  int col = (hh < NH) ? (hh * HD + 2 * f) : (E_D + (hh - NH) * HD + 2 * f);
  u32* p = (u32*)(QKV + (size_t)row * QW + col);
  u32 v = *p;
  float xr = bf16_f32((u16)(v & 0xffffu));
  float xi = bf16_f32((u16)(v >> 16));
  float c = cs[l * 64 + f], s = sn[l * 64 + f];
  float orr = xr * c - xi * s;
  float oii = xr * s + xi * c;
  *p = (u32)f32_bf16(orr) | ((u32)f32_bf16(oii) << 16);
}

// ---------------- C = A @ B^T, bf16 in, bf16 or f32 out ----------------
// 128x128 tile, BK=64, 4 waves, 32 KB LDS (m97/m103-proven geometry: the
// vmcnt+barrier drain is hidden by 4-5 co-resident blocks per CU — m114).
// NEW vs round-15: (1) XOR swizzle pair on the 128B LDS rows: staging
// pre-swizzles the SOURCE col (linear gload dest, rule #21) with key
// (row&7)<<4; frag reads apply the same XOR -> lanes 0-7 hit 8 distinct 16B
// slots (2-way residual = free). (2) XCD A-panel blocking: fid&7 = XCD owns
// 8 consecutive m-tiles (A-panel = 1024 rows x 2048 K x 2B = 4 MB = one L2).
template <int OUT_F32>
__global__ __launch_bounds__(256) void k_gemm_bt(
    const u16* __restrict__ A, int lda,
    const u16* __restrict__ B, int ldb,
    void* __restrict__ Cp, int ldc, int K) {
  __shared__ __align__(16) u16 As[128 * 64];
  __shared__ __align__(16) u16 Bs[128 * 64];
  const int tid = threadIdx.x;
  const int lane = tid & 63, w = tid >> 6;
  const int lr = lane & 15, lg = lane >> 4;
  const int fid = blockIdx.x;
  const int cc = fid & 7, l = fid >> 3;
  const int m0 = (cc * 8 + (l & 7)) * 128;   // 8 m-tiles per XCD
  const int n0 = (l >> 3) * 128;
  const int wm = (w >> 1) * 64, wn = (w & 1) * 64;
  const int srow8 = tid >> 3;                 // 0..31
  const f32x4 z4 = {0.f, 0.f, 0.f, 0.f};
  f32x4 acc[4][4];
#pragma unroll
  for (int i = 0; i < 4; ++i)
#pragma unroll
    for (int j = 0; j < 4; ++j) acc[i][j] = z4;
  for (int kt = 0; kt < K; kt += 64) {
#pragma unroll
    for (int rr = 0; rr < 4; ++rr) {
      int row = rr * 32 + srow8;
      int colb = ((tid & 7) * 16) ^ ((row & 7) << 4);  // pre-swizzled source col
      gload_lds16(A + (size_t)(m0 + row) * lda + kt + (colb >> 1),
                  (char*)As + rr * 4096 + w * 1024 + (lane << 4));
      gload_lds16(B + (size_t)(n0 + row) * ldb + kt + (colb >> 1),
                  (char*)Bs + rr * 4096 + w * 1024 + (lane << 4));
    }
    __syncthreads();
#pragma unroll
    for (int kk = 0; kk < 64; kk += 32) {
      short8 af[4], bfr[4];
#pragma unroll
      for (int mi = 0; mi < 4; ++mi) {
        int row = wm + mi * 16 + lr;
        af[mi] = *(const short8*)((const char*)As + row * 128 +
                                  (((kk * 2) + lg * 16) ^ ((row & 7) << 4)));
      }
#pragma unroll
      for (int ni = 0; ni < 4; ++ni) {
        int row = wn + ni * 16 + lr;
        bfr[ni] = *(const short8*)((const char*)Bs + row * 128 +
                                   (((kk * 2) + lg * 16) ^ ((row & 7) << 4)));
      }
#pragma unroll
      for (int mi = 0; mi < 4; ++mi)
#pragma unroll
        for (int ni = 0; ni < 4; ++ni)
          acc[mi][ni] =
              __builtin_amdgcn_mfma_f32_16x16x32_bf16(af[mi], bfr[ni], acc[mi][ni], 0, 0, 0);
    }
    __syncthreads();
  }
#pragma unroll
  for (int mi = 0; mi < 4; ++mi)
#pragma unroll
    for (int ni = 0; ni < 4; ++ni)
#pragma unroll
      for (int j = 0; j < 4; ++j) {
        size_t r = (size_t)(m0 + wm + mi * 16 + lg * 4 + j);
        int c = n0 + wn + ni * 16 + lr;
        if (OUT_F32)
          ((float*)Cp)[r * ldc + c] = acc[mi][ni][j];
        else
          ((u16*)Cp)[r * ldc + c] = f32_bf16(acc[mi][ni][j]);
      }
}

// ---------------- sliding-window flash attention (pipelined, 8 waves, 32x32 MFMA) ----
// (unchanged from rounds 15-18 — passing)
__global__ __launch_bounds__(512, 2) void k_attn(u16* __restrict__ QKV) {
  const int bx = blockIdx.x, h = blockIdx.y, b = blockIdx.z;
  const int qb = (b >= 2) ? 7 - bx : bx;        // cost-balanced remap
  const int tid = threadIdx.x;
  const int lane = tid & 63, w = tid >> 6;      // 8 waves
  const int l31 = lane & 31, hi = lane >> 5;
  const int kh = h >> 2;
  const int qs = qb * 256 + w * 32;
  __shared__ __align__(16) u16 Klds[2][64 * 128];  // [kv][d], swizzled, 2 buffers
  __shared__ __align__(16) u16 Vt[2][128 * 64];    // [d][kv], swizzled, 2 buffers
  const float SCL2 = 0.08838834764831845f * 1.4426950408889634f;  // scale*log2(e)
  const size_t bL = (size_t)b * L_S;
  const int q = qs + l31;
  const size_t rowQ = (bL + q) * QW + h * HD;
  short8 qf[8];
#pragma unroll
  for (int ds = 0; ds < 8; ++ds)
    qf[ds] = *(const short8*)(QKV + rowQ + ds * 16 + hi * 8);
  f32x16 o[4];
#pragma unroll
  for (int dt = 0; dt < 4; ++dt)
#pragma unroll
    for (int r = 0; r < 16; ++r) o[dt][r] = 0.f;
  float m2 = -3e38f, lsum = 0.f;  // per-lane stats for this lane's q (log2 domain)
  int t0 = qb * 256 - (WIN - 1);
  if (t0 < 0) t0 = 0;
  t0 >>= 6;
  const int t1 = 4 * qb + 3;  // == (qb*256+255)>>6
  short8 vreg[2];

  auto ISSUE_K = [&](int t, int buf) {
    char* Kb = (char*)Klds + buf * 16384;
#pragma unroll
    for (int rr = 0; rr < 2; ++rr) {
      int row = rr * 32 + (tid >> 4);              // 0..63
      int colb = ((tid & 15) * 16) ^ ((row & 7) << 4);  // inverse-swizzled source
      gload_lds16(QKV + (bL + t * 64 + row) * QW + E_D + kh * HD + (colb >> 1),
                  Kb + rr * 8192 + w * 1024 + (lane << 4));
    }
  };
  auto LOAD_V = [&](int t) {
#pragma unroll
    for (int rr = 0; rr < 2; ++rr)
      vreg[rr] = *(const short8*)(QKV + (bL + t * 64 + lane) * QW + E_D + 512 + kh * HD +
                                  ((w * 2 + rr) * 8));
  };
  auto WRITE_V = [&](int buf) {
    char* Vb = (char*)Vt + buf * 16384;
#pragma unroll
    for (int rr = 0; rr < 2; ++rr) {
      int db = (w * 2 + rr) * 8;                   // multiple of 8 -> row&7 == e
#pragma unroll
      for (int e = 0; e < 8; ++e)
        *(u16*)(Vb + ((((db + e) * 128) + lane * 2) ^ (e << 4))) = (u16)vreg[rr][e];
    }
  };

  LOAD_V(t0);
  ISSUE_K(t0, 0);
  __syncthreads();          // drains K gloads + V reg loads
  WRITE_V(0);               // Vt[0] = V(t0); published by barrier1 of iter t0
  int c = 0;

  for (int t = t0; t <= t1; ++t) {
    const int kv0 = t * 64;
    const int tn = (t < t1) ? t + 1 : t1;
    ISSUE_K(tn, c ^ 1);
    LOAD_V(tn);
    const bool act = (kv0 <= qs + 31) && (kv0 + 63 > qs - WIN);
    u32x4 pa[4];  // assembled PV A-frags (bf16 x8 each)
    if (act) {
      char* Kb = (char*)Klds + c * 16384;
      f32x16 s[2];
#pragma unroll
      for (int g = 0; g < 2; ++g)
#pragma unroll
        for (int r = 0; r < 16; ++r) s[g][r] = 0.f;
#pragma unroll
      for (int g = 0; g < 2; ++g) {
        const int r = g * 32 + l31;                  // K row this lane reads
        const int rsw = (r & 7) << 4;
#pragma unroll
        for (int ds = 0; ds < 8; ++ds) {
          short8 kf = *(const short8*)(Kb + (r * 256 + ((ds * 32 + hi * 16) ^ rsw)));
          s[g] = __builtin_amdgcn_mfma_f32_32x32x16_bf16(kf, qf[ds], s[g], 0, 0, 0);
        }
      }
      float v[2][16];
      float mx = -3e38f;
#pragma unroll
      for (int g = 0; g < 2; ++g)
#pragma unroll
        for (int r = 0; r < 16; ++r) {
          int kg = kv0 + g * 32 + (r & 3) + 8 * (r >> 2) + 4 * hi;
          bool a = (kg <= q) && (kg > q - WIN);
          float vv = a ? s[g][r] * SCL2 : -3e38f;
          v[g][r] = vv;
          mx = fmaxf(mx, vv);
        }
      mx = fmaxf(mx, __shfl_xor(mx, 32));            // partner has other kv half
      if (__ballot(mx > m2 + 11.5415603f)) {
        float mn = fmaxf(m2, mx);
        float alpha = exp2f(m2 - mn);
        m2 = mn;
        lsum *= alpha;
#pragma unroll
        for (int r = 0; r < 16; ++r) {
          float alr = __shfl(alpha, (r & 3) + 8 * (r >> 2) + 4 * hi);
#pragma unroll
          for (int dt = 0; dt < 4; ++dt) o[dt][r] *= alr;
        }
      }
      float rs = 0.f;
#pragma unroll
      for (int g = 0; g < 2; ++g)
#pragma unroll
        for (int r = 0; r < 16; ++r) {
          float pe = (v[g][r] > -1e37f) ? exp2f(v[g][r] - m2) : 0.f;
          v[g][r] = pe;
          rs += pe;
        }
      rs += __shfl_xor(rs, 32);
      lsum += rs;
#pragma unroll
      for (int g = 0; g < 2; ++g) {
        u32 W[8];
#pragma unroll
        for (int qi = 0; qi < 4; ++qi) {
          W[2 * qi]     = pack_bf16_pair(v[g][4 * qi + 0], v[g][4 * qi + 1]);
          W[2 * qi + 1] = pack_bf16_pair(v[g][4 * qi + 2], v[g][4 * qi + 3]);
        }
        u32 R[4];
        R[0] = __shfl_xor(hi ? W[0] : W[2], 32);
        R[1] = __shfl_xor(hi ? W[1] : W[3], 32);
        R[2] = __shfl_xor(hi ? W[4] : W[6], 32);
        R[3] = __shfl_xor(hi ? W[5] : W[7], 32);
#pragma unroll
        for (int ksl = 0; ksl < 2; ++ksl) {
          u32x4 fr;
          if (hi == 0) {
            fr[0] = W[4 * ksl]; fr[1] = W[4 * ksl + 1];
            fr[2] = R[2 * ksl]; fr[3] = R[2 * ksl + 1];
          } else {
            fr[0] = R[2 * ksl]; fr[1] = R[2 * ksl + 1];
            fr[2] = W[4 * ksl + 2]; fr[3] = W[4 * ksl + 3];
          }
          pa[g * 2 + ksl] = fr;
        }
      }
    }
    __syncthreads();  // barrier1: drains K(tn)+V(tn) loads; publishes Vt[c]; orders reuse
    WRITE_V(c ^ 1);   // stage V(tn) into spare buffer (PV below reads Vt[c])
    if (act) {
      char* Vb = (char*)Vt + c * 16384;
      __builtin_amdgcn_s_setprio(1);
#pragma unroll
      for (int dt = 0; dt < 4; ++dt) {
        const int d = dt * 32 + l31;
        const int dsw = (d & 7) << 4;
#pragma unroll
        for (int ks = 0; ks < 4; ++ks) {
          short8 vf = *(const short8*)(Vb + (d * 128 + ((ks * 32 + hi * 16) ^ dsw)));
          o[dt] = __builtin_amdgcn_mfma_f32_32x32x16_bf16(
              __builtin_bit_cast(short8, pa[ks]), vf, o[dt], 0, 0, 0);
        }
      }
      __builtin_amdgcn_s_setprio(0);
    }
    c ^= 1;
  }
  float inv = 1.0f / lsum;
#pragma unroll
  for (int r = 0; r < 16; ++r) {
    int ridx = (r & 3) + 8 * (r >> 2) + 4 * hi;
    float invr = __shfl(inv, ridx);
    size_t rowO = (bL + qs + ridx) * QW + h * HD + l31;
#pragma unroll
    for (int dt = 0; dt < 4; ++dt)
      QKV[rowO + dt * 32] = f32_bf16(o[dt][r] * invr);
  }
}

extern "C" void kernel_launch(void* const* d_in, const int* in_sizes, int n_in,
                              void* d_out, int out_size, void* d_ws, size_t ws_size,
                              hipStream_t stream) {
  const float* x  = (const float*)d_in[0];
  const float* Wq = (const float*)d_in[1];
  const float* Wk = (const float*)d_in[2];
  const float* Wv = (const float*)d_in[3];
  const float* Wo = (const float*)d_in[4];
  char* ws = (char*)d_ws;
  // Workspace layout (total 105,906,176 B). If the harness workspace is too
  // small, bail out cleanly (validation fails loudly instead of GPU faulting).
  if (ws_size < 105906176u) return;
  u16* xb    = (u16*)(ws);                    // 8192*2048*2 = 33554432
  u16* Wqkv  = (u16*)(ws + 33554432);         // 3072*2048*2 = 12582912
  u16* Wob   = (u16*)(ws + 46137344);         // 2048*2048*2 =  8388608
  u16* QKV   = (u16*)(ws + 54525952);         // 8192*3072*2 = 50331648
  float* cs  = (float*)(ws + 104857600);      // 131072*4    =   524288
  float* sn  = (float*)(ws + 105381888);      // total end 105906176 B

  // bf16 casts (weights packed: Wq rows 0..2047 | Wk rows 2048..2559 | Wv rows 2560..3071)
  k_cast<<<8192, 256, 0, stream>>>(x, xb, 16777216 / 8);
  k_cast<<<2048, 256, 0, stream>>>(Wq, Wqkv, 4194304 / 8);
  k_cast<<<512, 256, 0, stream>>>(Wk, Wqkv + 2048 * 2048, 1048576 / 8);
  k_cast<<<512, 256, 0, stream>>>(Wv, Wqkv + 2560 * 2048, 1048576 / 8);
  k_cast<<<2048, 256, 0, stream>>>(Wo, Wob, 4194304 / 8);
  k_rope_table<<<512, 256, 0, stream>>>(cs, sn);
  // fused QKV projection: [Q|K|V] = xb @ Wqkv^T (64 m x 24 n tiles; XCD panels)
  k_gemm_bt<0><<<1536, 256, 0, stream>>>(xb, 2048, Wqkv, 2048, QKV, QW, 2048);
  // RoPE in place on Q and K regions
  k_rope_apply<<<40960, 256, 0, stream>>>(QKV, cs, sn);
  // flash attention; Z overwrites Q region of QKV
  k_attn<<<dim3(8, 16, 4), 512, 0, stream>>>(QKV);
  // out = Z @ Wo^T (fp32 out; 64 m x 16 n tiles)
  k_gemm_bt<1><<<1024, 256, 0, stream>>>(QKV, QW, Wob, 2048, d_out, 2048, 2048);
}

// Round 20
// 390.470 us; speedup vs baseline: 1.2239x; 1.0069x over previous
//
#include <hip/hip_runtime.h>
#include <hip/hip_bf16.h>
#include <math.h>

typedef unsigned short u16;
typedef unsigned int u32;
typedef __attribute__((ext_vector_type(8))) short short8;
typedef __attribute__((ext_vector_type(8))) u16 ushort8;
typedef __attribute__((ext_vector_type(4))) float f32x4;
typedef __attribute__((ext_vector_type(16))) float f32x16;
typedef __attribute__((ext_vector_type(4))) u32 u32x4;

#define N_B 4
#define L_S 2048
#define E_D 2048
#define NH 16
#define HD 128
#define WIN 1024
#define QW 3072  // QKV buffer row width: 2048 q | 512 k | 512 v
#define LOG2E 1.4426950408889634f

static __device__ __forceinline__ u16 f32_bf16(float f) {
  u32 u = __builtin_bit_cast(u32, f);
  u = (u + 0x7fffu + ((u >> 16) & 1u)) >> 16;  // RNE
  return (u16)u;
}
static __device__ __forceinline__ float bf16_f32(u16 h) {
  u32 u = ((u32)h) << 16;
  return __builtin_bit_cast(float, u);
}
static __device__ __forceinline__ u32 pack_bf16_pair(float lo, float hi) {
  __hip_bfloat162 h2 = __float22bfloat162_rn(make_float2(lo, hi));  // RNE, .x = low
  u32 r;
  __builtin_memcpy(&r, &h2, 4);
  return r;
}
static __device__ __forceinline__ void gload_lds16(const void* g, void* l) {
  __builtin_amdgcn_global_load_lds((__attribute__((address_space(1))) void*)g,
                                   (__attribute__((address_space(3))) void*)l, 16, 0, 0);
}

// ---------------- fp32 -> bf16 cast (n multiple of 8) ----------------
__global__ void k_cast(const float* __restrict__ src, u16* __restrict__ dst, int n8) {
  int i = blockIdx.x * blockDim.x + threadIdx.x;
  if (i >= n8) return;
  const float4* s = (const float4*)src + (size_t)i * 2;
  float4 a = s[0], b = s[1];
  ushort8 v;
  v[0] = f32_bf16(a.x); v[1] = f32_bf16(a.y); v[2] = f32_bf16(a.z); v[3] = f32_bf16(a.w);
  v[4] = f32_bf16(b.x); v[5] = f32_bf16(b.y); v[6] = f32_bf16(b.z); v[7] = f32_bf16(b.w);
  *((ushort8*)dst + i) = v;
}

// ---------------- RoPE cos/sin table: [L][64] ----------------
__global__ void k_rope_table(float* __restrict__ cs, float* __restrict__ sn) {
  int idx = blockIdx.x * blockDim.x + threadIdx.x;  // 2048*64
  int l = idx >> 6, f = idx & 63;
  float freq = exp2f(-(float)f * (13.287712379549449f / 64.0f));  // 10000^(-2f/128)
  float ang = (float)l * freq;
  cs[idx] = cosf(ang);
  sn[idx] = sinf(ang);
}

// ---------------- interleaved RoPE applied in place to Q and K of QKV ----------------
__global__ void k_rope_apply(u16* __restrict__ QKV, const float* __restrict__ cs,
                             const float* __restrict__ sn) {
  int idx = blockIdx.x * blockDim.x + threadIdx.x;  // 8192*20*64 exactly
  int f = idx & 63;
  int rest = idx >> 6;
  int hh = rest % 20;          // 0..15 q heads, 16..19 kv heads
  int row = rest / 20;         // 0..8191 (= n*L + l)
  int l = row & (L_S - 1);
  int col = (hh < NH) ? (hh * HD + 2 * f) : (E_D + (hh - NH) * HD + 2 * f);
  u32* p = (u32*)(QKV + (size_t)row * QW + col);
  u32 v = *p;
  float xr = bf16_f32((u16)(v & 0xffffu));
  float xi = bf16_f32((u16)(v >> 16));
  float c = cs[l * 64 + f], s = sn[l * 64 + f];
  float orr = xr * c - xi * s;
  float oii = xr * s + xi * c;
  *p = (u32)f32_bf16(orr) | ((u32)f32_bf16(oii) << 16);
}

// ---------------- C = A @ B^T, bf16 in, bf16 or f32 out ----------------
// 128x128 tile, BK=64, 4 waves, 32 KB LDS (m97/m103-proven geometry: the
// vmcnt+barrier drain is hidden by 4-5 co-resident blocks per CU — m114).
// (1) XOR swizzle pair on the 128B LDS rows (pre-swizzled gload SOURCE with
// linear dest, rule #21; same XOR on frag reads). (2) XCD A-panel blocking:
// fid&7 = XCD owns 8 consecutive m-tiles (A-panel 4 MB = one L2).
// Round-19 verified: conflicts ~0, FETCH low, both GEMMs out of top-5.
template <int OUT_F32>
__global__ __launch_bounds__(256) void k_gemm_bt(
    const u16* __restrict__ A, int lda,
    const u16* __restrict__ B, int ldb,
    void* __restrict__ Cp, int ldc, int K) {
  __shared__ __align__(16) u16 As[128 * 64];
  __shared__ __align__(16) u16 Bs[128 * 64];
  const int tid = threadIdx.x;
  const int lane = tid & 63, w = tid >> 6;
  const int lr = lane & 15, lg = lane >> 4;
  const int fid = blockIdx.x;
  const int cc = fid & 7, l = fid >> 3;
  const int m0 = (cc * 8 + (l & 7)) * 128;   // 8 m-tiles per XCD
  const int n0 = (l >> 3) * 128;
  const int wm = (w >> 1) * 64, wn = (w & 1) * 64;
  const int srow8 = tid >> 3;                 // 0..31
  const f32x4 z4 = {0.f, 0.f, 0.f, 0.f};
  f32x4 acc[4][4];
#pragma unroll
  for (int i = 0; i < 4; ++i)
#pragma unroll
    for (int j = 0; j < 4; ++j) acc[i][j] = z4;
  for (int kt = 0; kt < K; kt += 64) {
#pragma unroll
    for (int rr = 0; rr < 4; ++rr) {
      int row = rr * 32 + srow8;
      int colb = ((tid & 7) * 16) ^ ((row & 7) << 4);  // pre-swizzled source col
      gload_lds16(A + (size_t)(m0 + row) * lda + kt + (colb >> 1),
                  (char*)As + rr * 4096 + w * 1024 + (lane << 4));
      gload_lds16(B + (size_t)(n0 + row) * ldb + kt + (colb >> 1),
                  (char*)Bs + rr * 4096 + w * 1024 + (lane << 4));
    }
    __syncthreads();
#pragma unroll
    for (int kk = 0; kk < 64; kk += 32) {
      short8 af[4], bfr[4];
#pragma unroll
      for (int mi = 0; mi < 4; ++mi) {
        int row = wm + mi * 16 + lr;
        af[mi] = *(const short8*)((const char*)As + row * 128 +
                                  (((kk * 2) + lg * 16) ^ ((row & 7) << 4)));
      }
#pragma unroll
      for (int ni = 0; ni < 4; ++ni) {
        int row = wn + ni * 16 + lr;
        bfr[ni] = *(const short8*)((const char*)Bs + row * 128 +
                                   (((kk * 2) + lg * 16) ^ ((row & 7) << 4)));
      }
#pragma unroll
      for (int mi = 0; mi < 4; ++mi)
#pragma unroll
        for (int ni = 0; ni < 4; ++ni)
          acc[mi][ni] =
              __builtin_amdgcn_mfma_f32_16x16x32_bf16(af[mi], bfr[ni], acc[mi][ni], 0, 0, 0);
    }
    __syncthreads();
  }
#pragma unroll
  for (int mi = 0; mi < 4; ++mi)
#pragma unroll
    for (int ni = 0; ni < 4; ++ni)
#pragma unroll
      for (int j = 0; j < 4; ++j) {
        size_t r = (size_t)(m0 + wm + mi * 16 + lg * 4 + j);
        int c = n0 + wn + ni * 16 + lr;
        if (OUT_F32)
          ((float*)Cp)[r * ldc + c] = acc[mi][ni][j];
        else
          ((u16*)Cp)[r * ldc + c] = f32_bf16(acc[mi][ni][j]);
      }
}

// ---------------- sliding-window flash attention (pipelined, 8 waves, 32x32 MFMA) ----
// Round-20 edits vs the passing r19 kernel (each independently audited):
//  (1) interior-tile fast path: wave-uniform `full` predicate
//      (kv0+63 <= qs && kv0 > qs+31-WIN) skips per-element masking + exp guard.
//  (2) WRITE_V moved AFTER the PV MFMA cluster (Vt[c^1] has no reader until
//      barrier1(t+1); PV(t) reads Vt[c] only) -> MFMA issues right at barrier.
//  (3) last-tile staging skipped (t<t1 guard) — the old duplicate prefetch of
//      t1 was wasted VMEM + a barrier drain covering nothing.
__global__ __launch_bounds__(512, 2) void k_attn(u16* __restrict__ QKV) {
  const int bx = blockIdx.x, h = blockIdx.y, b = blockIdx.z;
  const int qb = (b >= 2) ? 7 - bx : bx;        // cost-balanced remap
  const int tid = threadIdx.x;
  const int lane = tid & 63, w = tid >> 6;      // 8 waves
  const int l31 = lane & 31, hi = lane >> 5;
  const int kh = h >> 2;
  const int qs = qb * 256 + w * 32;
  __shared__ __align__(16) u16 Klds[2][64 * 128];  // [kv][d], swizzled, 2 buffers
  __shared__ __align__(16) u16 Vt[2][128 * 64];    // [d][kv], swizzled, 2 buffers
  const float SCL2 = 0.08838834764831845f * 1.4426950408889634f;  // scale*log2(e)
  const size_t bL = (size_t)b * L_S;
  const int q = qs + l31;
  const size_t rowQ = (bL + q) * QW + h * HD;
  short8 qf[8];
#pragma unroll
  for (int ds = 0; ds < 8; ++ds)
    qf[ds] = *(const short8*)(QKV + rowQ + ds * 16 + hi * 8);
  f32x16 o[4];
#pragma unroll
  for (int dt = 0; dt < 4; ++dt)
#pragma unroll
    for (int r = 0; r < 16; ++r) o[dt][r] = 0.f;
  float m2 = -3e38f, lsum = 0.f;  // per-lane stats for this lane's q (log2 domain)
  int t0 = qb * 256 - (WIN - 1);
  if (t0 < 0) t0 = 0;
  t0 >>= 6;
  const int t1 = 4 * qb + 3;  // == (qb*256+255)>>6
  short8 vreg[2];

  auto ISSUE_K = [&](int t, int buf) {
    char* Kb = (char*)Klds + buf * 16384;
#pragma unroll
    for (int rr = 0; rr < 2; ++rr) {
      int row = rr * 32 + (tid >> 4);              // 0..63
      int colb = ((tid & 15) * 16) ^ ((row & 7) << 4);  // inverse-swizzled source
      gload_lds16(QKV + (bL + t * 64 + row) * QW + E_D + kh * HD + (colb >> 1),
                  Kb + rr * 8192 + w * 1024 + (lane << 4));
    }
  };
  auto LOAD_V = [&](int t) {
#pragma unroll
    for (int rr = 0; rr < 2; ++rr)
      vreg[rr] = *(const short8*)(QKV + (bL + t * 64 + lane) * QW + E_D + 512 + kh * HD +
                                  ((w * 2 + rr) * 8));
  };
  auto WRITE_V = [&](int buf) {
    char* Vb = (char*)Vt + buf * 16384;
#pragma unroll
    for (int rr = 0; rr < 2; ++rr) {
      int db = (w * 2 + rr) * 8;                   // multiple of 8 -> row&7 == e
#pragma unroll
      for (int e = 0; e < 8; ++e)
        *(u16*)(Vb + ((((db + e) * 128) + lane * 2) ^ (e << 4))) = (u16)vreg[rr][e];
    }
  };

  LOAD_V(t0);
  ISSUE_K(t0, 0);
  __syncthreads();          // drains K gloads + V reg loads
  WRITE_V(0);               // Vt[0] = V(t0); published by barrier1 of iter t0
  int c = 0;

  for (int t = t0; t <= t1; ++t) {
    const int kv0 = t * 64;
    const bool lastt = (t == t1);
    if (!lastt) {           // prefetch next tile: K -> Klds[c^1], V -> regs
      ISSUE_K(t + 1, c ^ 1);
      LOAD_V(t + 1);
    }
    const bool act = (kv0 <= qs + 31) && (kv0 + 63 > qs - WIN);
    const bool full = (kv0 + 63 <= qs) && (kv0 > qs + 31 - WIN);  // no masking needed
    u32x4 pa[4];  // assembled PV A-frags (bf16 x8 each)
    if (act) {
      char* Kb = (char*)Klds + c * 16384;
      f32x16 s[2];
#pragma unroll
      for (int g = 0; g < 2; ++g)
#pragma unroll
        for (int r = 0; r < 16; ++r) s[g][r] = 0.f;
#pragma unroll
      for (int g = 0; g < 2; ++g) {
        const int r = g * 32 + l31;                  // K row this lane reads
        const int rsw = (r & 7) << 4;
#pragma unroll
        for (int ds = 0; ds < 8; ++ds) {
          short8 kf = *(const short8*)(Kb + (r * 256 + ((ds * 32 + hi * 16) ^ rsw)));
          s[g] = __builtin_amdgcn_mfma_f32_32x32x16_bf16(kf, qf[ds], s[g], 0, 0, 0);
        }
      }
      float v[2][16];
      float mx = -3e38f;
      if (full) {
#pragma unroll
        for (int g = 0; g < 2; ++g)
#pragma unroll
          for (int r = 0; r < 16; ++r) {
            float vv = s[g][r] * SCL2;
            v[g][r] = vv;
            mx = fmaxf(mx, vv);
          }
      } else {
#pragma unroll
        for (int g = 0; g < 2; ++g)
#pragma unroll
          for (int r = 0; r < 16; ++r) {
            int kg = kv0 + g * 32 + (r & 3) + 8 * (r >> 2) + 4 * hi;
            bool a = (kg <= q) && (kg > q - WIN);
            float vv = a ? s[g][r] * SCL2 : -3e38f;
            v[g][r] = vv;
            mx = fmaxf(mx, vv);
          }
      }
      mx = fmaxf(mx, __shfl_xor(mx, 32));            // partner has other kv half
      if (__ballot(mx > m2 + 11.5415603f)) {
        float mn = fmaxf(m2, mx);
        float alpha = exp2f(m2 - mn);
        m2 = mn;
        lsum *= alpha;
#pragma unroll
        for (int r = 0; r < 16; ++r) {
          float alr = __shfl(alpha, (r & 3) + 8 * (r >> 2) + 4 * hi);
#pragma unroll
          for (int dt = 0; dt < 4; ++dt) o[dt][r] *= alr;
        }
      }
      float rs = 0.f;
      if (full) {
#pragma unroll
        for (int g = 0; g < 2; ++g)
#pragma unroll
          for (int r = 0; r < 16; ++r) {
            float pe = exp2f(v[g][r] - m2);
            v[g][r] = pe;
            rs += pe;
          }
      } else {
#pragma unroll
        for (int g = 0; g < 2; ++g)
#pragma unroll
          for (int r = 0; r < 16; ++r) {
            float pe = (v[g][r] > -1e37f) ? exp2f(v[g][r] - m2) : 0.f;
            v[g][r] = pe;
            rs += pe;
          }
      }
      rs += __shfl_xor(rs, 32);
      lsum += rs;
#pragma unroll
      for (int g = 0; g < 2; ++g) {
        u32 W[8];
#pragma unroll
        for (int qi = 0; qi < 4; ++qi) {
          W[2 * qi]     = pack_bf16_pair(v[g][4 * qi + 0], v[g][4 * qi + 1]);
          W[2 * qi + 1] = pack_bf16_pair(v[g][4 * qi + 2], v[g][4 * qi + 3]);
        }
        u32 R[4];
        R[0] = __shfl_xor(hi ? W[0] : W[2], 32);
        R[1] = __shfl_xor(hi ? W[1] : W[3], 32);
        R[2] = __shfl_xor(hi ? W[4] : W[6], 32);
        R[3] = __shfl_xor(hi ? W[5] : W[7], 32);
#pragma unroll
        for (int ksl = 0; ksl < 2; ++ksl) {
          u32x4 fr;
          if (hi == 0) {
            fr[0] = W[4 * ksl]; fr[1] = W[4 * ksl + 1];
            fr[2] = R[2 * ksl]; fr[3] = R[2 * ksl + 1];
          } else {
            fr[0] = R[2 * ksl]; fr[1] = R[2 * ksl + 1];
            fr[2] = W[4 * ksl + 2]; fr[3] = W[4 * ksl + 3];
          }
          pa[g * 2 + ksl] = fr;
        }
      }
    }
    __syncthreads();  // barrier1: drains K/V prefetch loads; publishes Vt[c]; orders reuse
    if (act) {
      // --- O += P V from Vt[c] (MFMA issues immediately after barrier) ---
      char* Vb = (char*)Vt + c * 16384;
      __builtin_amdgcn_s_setprio(1);
#pragma unroll
      for (int dt = 0; dt < 4; ++dt) {
        const int d = dt * 32 + l31;
        const int dsw = (d & 7) << 4;
#pragma unroll
        for (int ks = 0; ks < 4; ++ks) {
          short8 vf = *(const short8*)(Vb + (d * 128 + ((ks * 32 + hi * 16) ^ dsw)));
          o[dt] = __builtin_amdgcn_mfma_f32_32x32x16_bf16(
              __builtin_bit_cast(short8, pa[ks]), vf, o[dt], 0, 0, 0);
        }
      }
      __builtin_amdgcn_s_setprio(0);
    }
    if (!lastt) WRITE_V(c ^ 1);  // stage V(t+1); readers gated by barrier1(t+1)
    c ^= 1;
  }
  float inv = 1.0f / lsum;
#pragma unroll
  for (int r = 0; r < 16; ++r) {
    int ridx = (r & 3) + 8 * (r >> 2) + 4 * hi;
    float invr = __shfl(inv, ridx);
    size_t rowO = (bL + qs + ridx) * QW + h * HD + l31;
#pragma unroll
    for (int dt = 0; dt < 4; ++dt)
      QKV[rowO + dt * 32] = f32_bf16(o[dt][r] * invr);
  }
}

extern "C" void kernel_launch(void* const* d_in, const int* in_sizes, int n_in,
                              void* d_out, int out_size, void* d_ws, size_t ws_size,
                              hipStream_t stream) {
  const float* x  = (const float*)d_in[0];
  const float* Wq = (const float*)d_in[1];
  const float* Wk = (const float*)d_in[2];
  const float* Wv = (const float*)d_in[3];
  const float* Wo = (const float*)d_in[4];
  char* ws = (char*)d_ws;
  // Workspace layout (total 105,906,176 B). If the harness workspace is too
  // small, bail out cleanly (validation fails loudly instead of GPU faulting).
  if (ws_size < 105906176u) return;
  u16* xb    = (u16*)(ws);                    // 8192*2048*2 = 33554432
  u16* Wqkv  = (u16*)(ws + 33554432);         // 3072*2048*2 = 12582912
  u16* Wob   = (u16*)(ws + 46137344);         // 2048*2048*2 =  8388608
  u16* QKV   = (u16*)(ws + 54525952);         // 8192*3072*2 = 50331648
  float* cs  = (float*)(ws + 104857600);      // 131072*4    =   524288
  float* sn  = (float*)(ws + 105381888);      // total end 105906176 B

  // bf16 casts (weights packed: Wq rows 0..2047 | Wk rows 2048..2559 | Wv rows 2560..3071)
  k_cast<<<8192, 256, 0, stream>>>(x, xb, 16777216 / 8);
  k_cast<<<2048, 256, 0, stream>>>(Wq, Wqkv, 4194304 / 8);
  k_cast<<<512, 256, 0, stream>>>(Wk, Wqkv + 2048 * 2048, 1048576 / 8);
  k_cast<<<512, 256, 0, stream>>>(Wv, Wqkv + 2560 * 2048, 1048576 / 8);
  k_cast<<<2048, 256, 0, stream>>>(Wo, Wob, 4194304 / 8);
  k_rope_table<<<512, 256, 0, stream>>>(cs, sn);
  // fused QKV projection: [Q|K|V] = xb @ Wqkv^T (64 m x 24 n tiles; XCD panels)
  k_gemm_bt<0><<<1536, 256, 0, stream>>>(xb, 2048, Wqkv, 2048, QKV, QW, 2048);
  // RoPE in place on Q and K regions
  k_rope_apply<<<40960, 256, 0, stream>>>(QKV, cs, sn);
  // flash attention; Z overwrites Q region of QKV
  k_attn<<<dim3(8, 16, 4), 512, 0, stream>>>(QKV);
  // out = Z @ Wo^T (fp32 out; 64 m x 16 n tiles)
  k_gemm_bt<1><<<1024, 256, 0, stream>>>(QKV, QW, Wob, 2048, d_out, 2048, 2048);
}

// Round 21
// 386.408 us; speedup vs baseline: 1.2367x; 1.0105x over previous
//
#include <hip/hip_runtime.h>
#include <hip/hip_bf16.h>
#include <math.h>

typedef unsigned short u16;
typedef unsigned int u32;
typedef __attribute__((ext_vector_type(8))) short short8;
typedef __attribute__((ext_vector_type(8))) u16 ushort8;
typedef __attribute__((ext_vector_type(4))) float f32x4;
typedef __attribute__((ext_vector_type(16))) float f32x16;
typedef __attribute__((ext_vector_type(4))) u32 u32x4;

#define N_B 4
#define L_S 2048
#define E_D 2048
#define NH 16
#define HD 128
#define WIN 1024
#define QW 3072  // QKV buffer row width: 2048 q | 512 k | 512 v
#define LOG2E 1.4426950408889634f

static __device__ __forceinline__ u16 f32_bf16(float f) {
  u32 u = __builtin_bit_cast(u32, f);
  u = (u + 0x7fffu + ((u >> 16) & 1u)) >> 16;  // RNE
  return (u16)u;
}
static __device__ __forceinline__ float bf16_f32(u16 h) {
  u32 u = ((u32)h) << 16;
  return __builtin_bit_cast(float, u);
}
static __device__ __forceinline__ u32 pack_bf16_pair(float lo, float hi) {
  __hip_bfloat162 h2 = __float22bfloat162_rn(make_float2(lo, hi));  // RNE, .x = low
  u32 r;
  __builtin_memcpy(&r, &h2, 4);
  return r;
}
static __device__ __forceinline__ void gload_lds16(const void* g, void* l) {
  __builtin_amdgcn_global_load_lds((__attribute__((address_space(1))) void*)g,
                                   (__attribute__((address_space(3))) void*)l, 16, 0, 0);
}

// ---------------- fp32 -> bf16 cast (n multiple of 8) ----------------
__global__ void k_cast(const float* __restrict__ src, u16* __restrict__ dst, int n8) {
  int i = blockIdx.x * blockDim.x + threadIdx.x;
  if (i >= n8) return;
  const float4* s = (const float4*)src + (size_t)i * 2;
  float4 a = s[0], b = s[1];
  ushort8 v;
  v[0] = f32_bf16(a.x); v[1] = f32_bf16(a.y); v[2] = f32_bf16(a.z); v[3] = f32_bf16(a.w);
  v[4] = f32_bf16(b.x); v[5] = f32_bf16(b.y); v[6] = f32_bf16(b.z); v[7] = f32_bf16(b.w);
  *((ushort8*)dst + i) = v;
}

// ---------------- RoPE cos/sin table: [L][64] ----------------
__global__ void k_rope_table(float* __restrict__ cs, float* __restrict__ sn) {
  int idx = blockIdx.x * blockDim.x + threadIdx.x;  // 2048*64
  int l = idx >> 6, f = idx & 63;
  float freq = exp2f(-(float)f * (13.287712379549449f / 64.0f));  // 10000^(-2f/128)
  float ang = (float)l * freq;
  cs[idx] = cosf(ang);
  sn[idx] = sinf(ang);
}

// ---------------- interleaved RoPE applied in place to K region of QKV --------------
// (Q rope is fused into k_attn's register Q load — lane-local pairs, no extra pass.)
__global__ void k_rope_k(u16* __restrict__ QKV, const float* __restrict__ cs,
                         const float* __restrict__ sn) {
  int idx = blockIdx.x * blockDim.x + threadIdx.x;  // 8192*4*64 exactly
  int f = idx & 63;
  int rest = idx >> 6;
  int hh = rest & 3;           // kv head 0..3
  int row = rest >> 2;         // 0..8191 (= n*L + l)
  int l = row & (L_S - 1);
  int col = E_D + hh * HD + 2 * f;
  u32* p = (u32*)(QKV + (size_t)row * QW + col);
  u32 v = *p;
  float xr = bf16_f32((u16)(v & 0xffffu));
  float xi = bf16_f32((u16)(v >> 16));
  float c = cs[l * 64 + f], s = sn[l * 64 + f];
  float orr = xr * c - xi * s;
  float oii = xr * s + xi * c;
  *p = (u32)f32_bf16(orr) | ((u32)f32_bf16(oii) << 16);
}

// ---------------- C = A @ B^T, bf16 in, bf16 or f32 out ----------------
// 128x128 tile, BK=64, 4 waves, 32 KB LDS (m97/m103-proven geometry).
// XOR swizzle pair on the 128B LDS rows + XCD A-panel blocking.
// Round-19 verified: conflicts ~0, FETCH low, both GEMMs out of top-5.
template <int OUT_F32>
__global__ __launch_bounds__(256) void k_gemm_bt(
    const u16* __restrict__ A, int lda,
    const u16* __restrict__ B, int ldb,
    void* __restrict__ Cp, int ldc, int K) {
  __shared__ __align__(16) u16 As[128 * 64];
  __shared__ __align__(16) u16 Bs[128 * 64];
  const int tid = threadIdx.x;
  const int lane = tid & 63, w = tid >> 6;
  const int lr = lane & 15, lg = lane >> 4;
  const int fid = blockIdx.x;
  const int cc = fid & 7, l = fid >> 3;
  const int m0 = (cc * 8 + (l & 7)) * 128;   // 8 m-tiles per XCD
  const int n0 = (l >> 3) * 128;
  const int wm = (w >> 1) * 64, wn = (w & 1) * 64;
  const int srow8 = tid >> 3;                 // 0..31
  const f32x4 z4 = {0.f, 0.f, 0.f, 0.f};
  f32x4 acc[4][4];
#pragma unroll
  for (int i = 0; i < 4; ++i)
#pragma unroll
    for (int j = 0; j < 4; ++j) acc[i][j] = z4;
  for (int kt = 0; kt < K; kt += 64) {
#pragma unroll
    for (int rr = 0; rr < 4; ++rr) {
      int row = rr * 32 + srow8;
      int colb = ((tid & 7) * 16) ^ ((row & 7) << 4);  // pre-swizzled source col
      gload_lds16(A + (size_t)(m0 + row) * lda + kt + (colb >> 1),
                  (char*)As + rr * 4096 + w * 1024 + (lane << 4));
      gload_lds16(B + (size_t)(n0 + row) * ldb + kt + (colb >> 1),
                  (char*)Bs + rr * 4096 + w * 1024 + (lane << 4));
    }
    __syncthreads();
#pragma unroll
    for (int kk = 0; kk < 64; kk += 32) {
      short8 af[4], bfr[4];
#pragma unroll
      for (int mi = 0; mi < 4; ++mi) {
        int row = wm + mi * 16 + lr;
        af[mi] = *(const short8*)((const char*)As + row * 128 +
                                  (((kk * 2) + lg * 16) ^ ((row & 7) << 4)));
      }
#pragma unroll
      for (int ni = 0; ni < 4; ++ni) {
        int row = wn + ni * 16 + lr;
        bfr[ni] = *(const short8*)((const char*)Bs + row * 128 +
                                   (((kk * 2) + lg * 16) ^ ((row & 7) << 4)));
      }
#pragma unroll
      for (int mi = 0; mi < 4; ++mi)
#pragma unroll
        for (int ni = 0; ni < 4; ++ni)
          acc[mi][ni] =
              __builtin_amdgcn_mfma_f32_16x16x32_bf16(af[mi], bfr[ni], acc[mi][ni], 0, 0, 0);
    }
    __syncthreads();
  }
#pragma unroll
  for (int mi = 0; mi < 4; ++mi)
#pragma unroll
    for (int ni = 0; ni < 4; ++ni)
#pragma unroll
      for (int j = 0; j < 4; ++j) {
        size_t r = (size_t)(m0 + wm + mi * 16 + lg * 4 + j);
        int c = n0 + wn + ni * 16 + lr;
        if (OUT_F32)
          ((float*)Cp)[r * ldc + c] = acc[mi][ni][j];
        else
          ((u16*)Cp)[r * ldc + c] = f32_bf16(acc[mi][ni][j]);
      }
}

// ---------------- sliding-window flash attention (pipelined, 8 waves, 32x32 MFMA) ----
// r21: Q-rope fused into the register Q load (lane-local: qf[ds] holds 8
// consecutive head-dim cols = 4 interleaved pairs; 2 float4 table loads + 4
// rotations per ds, once per block). Everything else identical to r20.
__global__ __launch_bounds__(512, 2) void k_attn(u16* __restrict__ QKV,
                                                 const float* __restrict__ cs,
                                                 const float* __restrict__ sn) {
  const int bx = blockIdx.x, h = blockIdx.y, b = blockIdx.z;
  const int qb = (b >= 2) ? 7 - bx : bx;        // cost-balanced remap
  const int tid = threadIdx.x;
  const int lane = tid & 63, w = tid >> 6;      // 8 waves
  const int l31 = lane & 31, hi = lane >> 5;
  const int kh = h >> 2;
  const int qs = qb * 256 + w * 32;
  __shared__ __align__(16) u16 Klds[2][64 * 128];  // [kv][d], swizzled, 2 buffers
  __shared__ __align__(16) u16 Vt[2][128 * 64];    // [d][kv], swizzled, 2 buffers
  const float SCL2 = 0.08838834764831845f * 1.4426950408889634f;  // scale*log2(e)
  const size_t bL = (size_t)b * L_S;
  const int q = qs + l31;
  const size_t rowQ = (bL + q) * QW + h * HD;
  // Q load + fused interleaved RoPE (d = ds*16+hi*8+j; pair f = d>>1)
  short8 qf[8];
#pragma unroll
  for (int ds = 0; ds < 8; ++ds) {
    short8 qr = *(const short8*)(QKV + rowQ + ds * 16 + hi * 8);
    const int f0 = ds * 8 + hi * 4;                   // first pair index (mult of 4)
    float4 c4 = *(const float4*)(cs + (size_t)q * 64 + f0);
    float4 s4 = *(const float4*)(sn + (size_t)q * 64 + f0);
    ushort8 qo;
#pragma unroll
    for (int e = 0; e < 4; ++e) {
      float xr = bf16_f32((u16)qr[2 * e]);
      float xi = bf16_f32((u16)qr[2 * e + 1]);
      float co = (e == 0) ? c4.x : (e == 1) ? c4.y : (e == 2) ? c4.z : c4.w;
      float si = (e == 0) ? s4.x : (e == 1) ? s4.y : (e == 2) ? s4.z : s4.w;
      qo[2 * e]     = f32_bf16(xr * co - xi * si);
      qo[2 * e + 1] = f32_bf16(xr * si + xi * co);
    }
    qf[ds] = __builtin_bit_cast(short8, qo);
  }
  f32x16 o[4];
#pragma unroll
  for (int dt = 0; dt < 4; ++dt)
#pragma unroll
    for (int r = 0; r < 16; ++r) o[dt][r] = 0.f;
  float m2 = -3e38f, lsum = 0.f;  // per-lane stats for this lane's q (log2 domain)
  int t0 = qb * 256 - (WIN - 1);
  if (t0 < 0) t0 = 0;
  t0 >>= 6;
  const int t1 = 4 * qb + 3;  // == (qb*256+255)>>6
  short8 vreg[2];

  auto ISSUE_K = [&](int t, int buf) {
    char* Kb = (char*)Klds + buf * 16384;
#pragma unroll
    for (int rr = 0; rr < 2; ++rr) {
      int row = rr * 32 + (tid >> 4);              // 0..63
      int colb = ((tid & 15) * 16) ^ ((row & 7) << 4);  // inverse-swizzled source
      gload_lds16(QKV + (bL + t * 64 + row) * QW + E_D + kh * HD + (colb >> 1),
                  Kb + rr * 8192 + w * 1024 + (lane << 4));
    }
  };
  auto LOAD_V = [&](int t) {
#pragma unroll
    for (int rr = 0; rr < 2; ++rr)
      vreg[rr] = *(const short8*)(QKV + (bL + t * 64 + lane) * QW + E_D + 512 + kh * HD +
                                  ((w * 2 + rr) * 8));
  };
  auto WRITE_V = [&](int buf) {
    char* Vb = (char*)Vt + buf * 16384;
#pragma unroll
    for (int rr = 0; rr < 2; ++rr) {
      int db = (w * 2 + rr) * 8;                   // multiple of 8 -> row&7 == e
#pragma unroll
      for (int e = 0; e < 8; ++e)
        *(u16*)(Vb + ((((db + e) * 128) + lane * 2) ^ (e << 4))) = (u16)vreg[rr][e];
    }
  };

  LOAD_V(t0);
  ISSUE_K(t0, 0);
  __syncthreads();          // drains K gloads + V reg loads
  WRITE_V(0);               // Vt[0] = V(t0); published by barrier1 of iter t0
  int c = 0;

  for (int t = t0; t <= t1; ++t) {
    const int kv0 = t * 64;
    const bool lastt = (t == t1);
    if (!lastt) {           // prefetch next tile: K -> Klds[c^1], V -> regs
      ISSUE_K(t + 1, c ^ 1);
      LOAD_V(t + 1);
    }
    const bool act = (kv0 <= qs + 31) && (kv0 + 63 > qs - WIN);
    const bool full = (kv0 + 63 <= qs) && (kv0 > qs + 31 - WIN);  // no masking needed
    u32x4 pa[4];  // assembled PV A-frags (bf16 x8 each)
    if (act) {
      char* Kb = (char*)Klds + c * 16384;
      f32x16 s[2];
#pragma unroll
      for (int g = 0; g < 2; ++g)
#pragma unroll
        for (int r = 0; r < 16; ++r) s[g][r] = 0.f;
#pragma unroll
      for (int g = 0; g < 2; ++g) {
        const int r = g * 32 + l31;                  // K row this lane reads
        const int rsw = (r & 7) << 4;
#pragma unroll
        for (int ds = 0; ds < 8; ++ds) {
          short8 kf = *(const short8*)(Kb + (r * 256 + ((ds * 32 + hi * 16) ^ rsw)));
          s[g] = __builtin_amdgcn_mfma_f32_32x32x16_bf16(kf, qf[ds], s[g], 0, 0, 0);
        }
      }
      float v[2][16];
      float mx = -3e38f;
      if (full) {
#pragma unroll
        for (int g = 0; g < 2; ++g)
#pragma unroll
          for (int r = 0; r < 16; ++r) {
            float vv = s[g][r] * SCL2;
            v[g][r] = vv;
            mx = fmaxf(mx, vv);
          }
      } else {
#pragma unroll
        for (int g = 0; g < 2; ++g)
#pragma unroll
          for (int r = 0; r < 16; ++r) {
            int kg = kv0 + g * 32 + (r & 3) + 8 * (r >> 2) + 4 * hi;
            bool a = (kg <= q) && (kg > q - WIN);
            float vv = a ? s[g][r] * SCL2 : -3e38f;
            v[g][r] = vv;
            mx = fmaxf(mx, vv);
          }
      }
      mx = fmaxf(mx, __shfl_xor(mx, 32));            // partner has other kv half
      if (__ballot(mx > m2 + 11.5415603f)) {
        float mn = fmaxf(m2, mx);
        float alpha = exp2f(m2 - mn);
        m2 = mn;
        lsum *= alpha;
#pragma unroll
        for (int r = 0; r < 16; ++r) {
          float alr = __shfl(alpha, (r & 3) + 8 * (r >> 2) + 4 * hi);
#pragma unroll
          for (int dt = 0; dt < 4; ++dt) o[dt][r] *= alr;
        }
      }
      float rs = 0.f;
      if (full) {
#pragma unroll
        for (int g = 0; g < 2; ++g)
#pragma unroll
          for (int r = 0; r < 16; ++r) {
            float pe = exp2f(v[g][r] - m2);
            v[g][r] = pe;
            rs += pe;
          }
      } else {
#pragma unroll
        for (int g = 0; g < 2; ++g)
#pragma unroll
          for (int r = 0; r < 16; ++r) {
            float pe = (v[g][r] > -1e37f) ? exp2f(v[g][r] - m2) : 0.f;
            v[g][r] = pe;
            rs += pe;
          }
      }
      rs += __shfl_xor(rs, 32);
      lsum += rs;
#pragma unroll
      for (int g = 0; g < 2; ++g) {
        u32 W[8];
#pragma unroll
        for (int qi = 0; qi < 4; ++qi) {
          W[2 * qi]     = pack_bf16_pair(v[g][4 * qi + 0], v[g][4 * qi + 1]);
          W[2 * qi + 1] = pack_bf16_pair(v[g][4 * qi + 2], v[g][4 * qi + 3]);
        }
        u32 R[4];
        R[0] = __shfl_xor(hi ? W[0] : W[2], 32);
        R[1] = __shfl_xor(hi ? W[1] : W[3], 32);
        R[2] = __shfl_xor(hi ? W[4] : W[6], 32);
        R[3] = __shfl_xor(hi ? W[5] : W[7], 32);
#pragma unroll
        for (int ksl = 0; ksl < 2; ++ksl) {
          u32x4 fr;
          if (hi == 0) {
            fr[0] = W[4 * ksl]; fr[1] = W[4 * ksl + 1];
            fr[2] = R[2 * ksl]; fr[3] = R[2 * ksl + 1];
          } else {
            fr[0] = R[2 * ksl]; fr[1] = R[2 * ksl + 1];
            fr[2] = W[4 * ksl + 2]; fr[3] = W[4 * ksl + 3];
          }
          pa[g * 2 + ksl] = fr;
        }
      }
    }
    __syncthreads();  // barrier1: drains K/V prefetch loads; publishes Vt[c]; orders reuse
    if (act) {
      // --- O += P V from Vt[c] (MFMA issues immediately after barrier) ---
      char* Vb = (char*)Vt + c * 16384;
      __builtin_amdgcn_s_setprio(1);
#pragma unroll
      for (int dt = 0; dt < 4; ++dt) {
        const int d = dt * 32 + l31;
        const int dsw = (d & 7) << 4;
#pragma unroll
        for (int ks = 0; ks < 4; ++ks) {
          short8 vf = *(const short8*)(Vb + (d * 128 + ((ks * 32 + hi * 16) ^ dsw)));
          o[dt] = __builtin_amdgcn_mfma_f32_32x32x16_bf16(
              __builtin_bit_cast(short8, pa[ks]), vf, o[dt], 0, 0, 0);
        }
      }
      __builtin_amdgcn_s_setprio(0);
    }
    if (!lastt) WRITE_V(c ^ 1);  // stage V(t+1); readers gated by barrier1(t+1)
    c ^= 1;
  }
  float inv = 1.0f / lsum;
#pragma unroll
  for (int r = 0; r < 16; ++r) {
    int ridx = (r & 3) + 8 * (r >> 2) + 4 * hi;
    float invr = __shfl(inv, ridx);
    size_t rowO = (bL + qs + ridx) * QW + h * HD + l31;
#pragma unroll
    for (int dt = 0; dt < 4; ++dt)
      QKV[rowO + dt * 32] = f32_bf16(o[dt][r] * invr);
  }
}

extern "C" void kernel_launch(void* const* d_in, const int* in_sizes, int n_in,
                              void* d_out, int out_size, void* d_ws, size_t ws_size,
                              hipStream_t stream) {
  const float* x  = (const float*)d_in[0];
  const float* Wq = (const float*)d_in[1];
  const float* Wk = (const float*)d_in[2];
  const float* Wv = (const float*)d_in[3];
  const float* Wo = (const float*)d_in[4];
  char* ws = (char*)d_ws;
  // Workspace layout (total 105,906,176 B). If the harness workspace is too
  // small, bail out cleanly (validation fails loudly instead of GPU faulting).
  if (ws_size < 105906176u) return;
  u16* xb    = (u16*)(ws);                    // 8192*2048*2 = 33554432
  u16* Wqkv  = (u16*)(ws + 33554432);         // 3072*2048*2 = 12582912
  u16* Wob   = (u16*)(ws + 46137344);         // 2048*2048*2 =  8388608
  u16* QKV   = (u16*)(ws + 54525952);         // 8192*3072*2 = 50331648
  float* cs  = (float*)(ws + 104857600);      // 131072*4    =   524288
  float* sn  = (float*)(ws + 105381888);      // total end 105906176 B

  // bf16 casts (weights packed: Wq rows 0..2047 | Wk rows 2048..2559 | Wv rows 2560..3071)
  k_cast<<<8192, 256, 0, stream>>>(x, xb, 16777216 / 8);
  k_cast<<<2048, 256, 0, stream>>>(Wq, Wqkv, 4194304 / 8);
  k_cast<<<512, 256, 0, stream>>>(Wk, Wqkv + 2048 * 2048, 1048576 / 8);
  k_cast<<<512, 256, 0, stream>>>(Wv, Wqkv + 2560 * 2048, 1048576 / 8);
  k_cast<<<2048, 256, 0, stream>>>(Wo, Wob, 4194304 / 8);
  k_rope_table<<<512, 256, 0, stream>>>(cs, sn);
  // fused QKV projection: [Q|K|V] = xb @ Wqkv^T (64 m x 24 n tiles; XCD panels)
  k_gemm_bt<0><<<1536, 256, 0, stream>>>(xb, 2048, Wqkv, 2048, QKV, QW, 2048);
  // RoPE in place on K region only (Q rope fused into k_attn)
  k_rope_k<<<8192, 256, 0, stream>>>(QKV, cs, sn);
  // flash attention (Q-rope fused); Z overwrites Q region of QKV
  k_attn<<<dim3(8, 16, 4), 512, 0, stream>>>(QKV, cs, sn);
  // out = Z @ Wo^T (fp32 out; 64 m x 16 n tiles)
  k_gemm_bt<1><<<1024, 256, 0, stream>>>(QKV, QW, Wob, 2048, d_out, 2048, 2048);
}

// Round 22
// 375.963 us; speedup vs baseline: 1.2711x; 1.0278x over previous
//
#include <hip/hip_runtime.h>
#include <hip/hip_bf16.h>
#include <math.h>

typedef unsigned short u16;
typedef unsigned int u32;
typedef __attribute__((ext_vector_type(8))) short short8;
typedef __attribute__((ext_vector_type(8))) u16 ushort8;
typedef __attribute__((ext_vector_type(4))) float f32x4;
typedef __attribute__((ext_vector_type(16))) float f32x16;
typedef __attribute__((ext_vector_type(4))) u32 u32x4;

#define N_B 4
#define L_S 2048
#define E_D 2048
#define NH 16
#define HD 128
#define WIN 1024
#define QW 3072  // QKV buffer row width: 2048 q | 512 k | 512 v
#define LOG2E 1.4426950408889634f

static __device__ __forceinline__ u16 f32_bf16(float f) {
  u32 u = __builtin_bit_cast(u32, f);
  u = (u + 0x7fffu + ((u >> 16) & 1u)) >> 16;  // RNE
  return (u16)u;
}
static __device__ __forceinline__ float bf16_f32(u16 h) {
  u32 u = ((u32)h) << 16;
  return __builtin_bit_cast(float, u);
}
static __device__ __forceinline__ u32 pack_bf16_pair(float lo, float hi) {
  __hip_bfloat162 h2 = __float22bfloat162_rn(make_float2(lo, hi));  // RNE, .x = low
  u32 r;
  __builtin_memcpy(&r, &h2, 4);
  return r;
}
static __device__ __forceinline__ void gload_lds16(const void* g, void* l) {
  __builtin_amdgcn_global_load_lds((__attribute__((address_space(1))) void*)g,
                                   (__attribute__((address_space(3))) void*)l, 16, 0, 0);
}

// ---------------- fp32 -> bf16 cast (n multiple of 8) ----------------
__global__ void k_cast(const float* __restrict__ src, u16* __restrict__ dst, int n8) {
  int i = blockIdx.x * blockDim.x + threadIdx.x;
  if (i >= n8) return;
  const float4* s = (const float4*)src + (size_t)i * 2;
  float4 a = s[0], b = s[1];
  ushort8 v;
  v[0] = f32_bf16(a.x); v[1] = f32_bf16(a.y); v[2] = f32_bf16(a.z); v[3] = f32_bf16(a.w);
  v[4] = f32_bf16(b.x); v[5] = f32_bf16(b.y); v[6] = f32_bf16(b.z); v[7] = f32_bf16(b.w);
  *((ushort8*)dst + i) = v;
}

// ---------------- RoPE cos/sin table: [L][64] ----------------
__global__ void k_rope_table(float* __restrict__ cs, float* __restrict__ sn) {
  int idx = blockIdx.x * blockDim.x + threadIdx.x;  // 2048*64
  int l = idx >> 6, f = idx & 63;
  float freq = exp2f(-(float)f * (13.287712379549449f / 64.0f));  // 10000^(-2f/128)
  float ang = (float)l * freq;
  cs[idx] = cosf(ang);
  sn[idx] = sinf(ang);
}

// ---------------- interleaved RoPE applied in place to K region of QKV --------------
// (Q rope is fused into k_attn's register Q load — lane-local pairs, no extra pass.)
__global__ void k_rope_k(u16* __restrict__ QKV, const float* __restrict__ cs,
                         const float* __restrict__ sn) {
  int idx = blockIdx.x * blockDim.x + threadIdx.x;  // 8192*4*64 exactly
  int f = idx & 63;
  int rest = idx >> 6;
  int hh = rest & 3;           // kv head 0..3
  int row = rest >> 2;         // 0..8191 (= n*L + l)
  int l = row & (L_S - 1);
  int col = E_D + hh * HD + 2 * f;
  u32* p = (u32*)(QKV + (size_t)row * QW + col);
  u32 v = *p;
  float xr = bf16_f32((u16)(v & 0xffffu));
  float xi = bf16_f32((u16)(v >> 16));
  float c = cs[l * 64 + f], s = sn[l * 64 + f];
  float orr = xr * c - xi * s;
  float oii = xr * s + xi * c;
  *p = (u32)f32_bf16(orr) | ((u32)f32_bf16(oii) << 16);
}

// ---------------- C = A @ B^T, 256x256 tile, BK=32, 8-phase counted-vmcnt ----
// Mechanical transform of the round-16 kernel (measured: 0 bank conflicts,
// FETCH 82MB) into the m201 phase template. Addressing/staging/swizzle are
// byte-identical to r16; ONLY the inner loop is restructured:
//   per K-tile, 2 phases x { ds_reads -> stage 2 gloads -> barrier ->
//     lgkmcnt(0) AFTER barrier (r17 bug fixed) -> setprio+16 MFMA -> barrier }.
//   B-frags read once in phase 0, carried in registers for phase 1.
//   vmcnt(4) ONCE per tile (phase 1), never 0 in-loop: tile t stages t+2
//   (A ph0, B ph1); outstanding 8 -> vmcnt(4) publishes t+1, keeps t+2 flying.
// Hazards: RAW — t's reads from buf staged at t-2, drained vmcnt@t-1/ph1 before
// its barrier. WAR — STAGE(t+2)->buf (t-1)%3; all t-1 reads landed at t-1/ph1
// lgkmcnt(0), which precedes the second barrier every wave crosses before t/ph0.
template <int OUT_F32>
__global__ __launch_bounds__(512, 1) void k_gemm8(
    const u16* __restrict__ A, int lda,
    const u16* __restrict__ B, int ldb,
    void* __restrict__ Cp, int ldc, int K) {
  __shared__ __align__(16) u16 Ab[3 * 8192];  // 3 x [256][32]
  __shared__ __align__(16) u16 Bb[3 * 8192];
  const int tid = threadIdx.x;
  const int lane = tid & 63, w = tid >> 6;
  const int lr = lane & 15, lg = lane >> 4;
  const int wm = w >> 2, wn = w & 3;
  const int fid = blockIdx.x;
  const int cc = fid & 7, l = fid >> 3;
  const int m0 = (cc * 4 + (l & 3)) * 256;
  const int n0 = (l >> 2) * 256;
  const int rswz = (lr & 6) << 3;  // read-side XOR (row bits 1-2)

  const int r2 = tid >> 2;                                   // 0..127
  const int ce = (((tid & 3) * 16) ^ ((r2 & 6) << 3)) >> 1;  // pre-swizzled src col
  auto STAGE_A = [&](int kt, int bb) {
#pragma unroll
    for (int rr = 0; rr < 2; ++rr)
      gload_lds16(A + (size_t)(m0 + rr * 128 + r2) * lda + kt * 32 + ce,
                  (char*)Ab + bb * 16384 + rr * 8192 + (w << 10));
  };
  auto STAGE_B = [&](int kt, int bb) {
#pragma unroll
    for (int rr = 0; rr < 2; ++rr)
      gload_lds16(B + (size_t)(n0 + rr * 128 + r2) * ldb + kt * 32 + ce,
                  (char*)Bb + bb * 16384 + rr * 8192 + (w << 10));
  };

  f32x4 acc[8][4];
  const f32x4 z4 = {0.f, 0.f, 0.f, 0.f};
#pragma unroll
  for (int mf = 0; mf < 8; ++mf)
#pragma unroll
    for (int nf = 0; nf < 4; ++nf) acc[mf][nf] = z4;

  const int nt = K >> 5;  // K-tiles of 32 (K=2048 -> 64)
  STAGE_A(0, 0); STAGE_B(0, 0);
  STAGE_A(1, 1); STAGE_B(1, 1);
  asm volatile("s_waitcnt vmcnt(4)" ::: "memory");  // tile0 published; tile1 in flight
  __builtin_amdgcn_sched_barrier(0);
  __builtin_amdgcn_s_barrier();
  __builtin_amdgcn_sched_barrier(0);

  int c3 = 0;
  for (int t = 0; t < nt; ++t) {
    int ib = c3 + 2; if (ib >= 3) ib -= 3;
    const char* Abt = (const char*)Ab + c3 * 16384;
    const char* Bbt = (const char*)Bb + c3 * 16384;
    short8 af[4], bf[4];
    // ---- phase 0: quadrant qm=0 ----
#pragma unroll
    for (int nf = 0; nf < 4; ++nf) {
      int row = wn * 64 + nf * 16 + lr;
      bf[nf] = *(const short8*)(Bbt + row * 64 + ((lg * 16) ^ rswz));
    }
#pragma unroll
    for (int mf = 0; mf < 4; ++mf) {
      int row = wm * 128 + mf * 16 + lr;
      af[mf] = *(const short8*)(Abt + row * 64 + ((lg * 16) ^ rswz));
    }
    if (t + 2 < nt) STAGE_A(t + 2, ib);
    __builtin_amdgcn_sched_barrier(0);
    __builtin_amdgcn_s_barrier();
    asm volatile("s_waitcnt lgkmcnt(0)" ::: "memory");
    __builtin_amdgcn_sched_barrier(0);
    __builtin_amdgcn_s_setprio(1);
#pragma unroll
    for (int mf = 0; mf < 4; ++mf)
#pragma unroll
      for (int nf = 0; nf < 4; ++nf)
        acc[mf][nf] =
            __builtin_amdgcn_mfma_f32_16x16x32_bf16(af[mf], bf[nf], acc[mf][nf], 0, 0, 0);
    __builtin_amdgcn_s_setprio(0);
    __builtin_amdgcn_sched_barrier(0);
    __builtin_amdgcn_s_barrier();
    __builtin_amdgcn_sched_barrier(0);
    // ---- phase 1: quadrant qm=1 (bf carried in registers) ----
#pragma unroll
    for (int mf = 0; mf < 4; ++mf) {
      int row = wm * 128 + 64 + mf * 16 + lr;
      af[mf] = *(const short8*)(Abt + row * 64 + ((lg * 16) ^ rswz));
    }
    if (t + 2 < nt) STAGE_B(t + 2, ib);
    if (t + 2 < nt)
      asm volatile("s_waitcnt vmcnt(4)" ::: "memory");
    else
      asm volatile("s_waitcnt vmcnt(0)" ::: "memory");
    __builtin_amdgcn_sched_barrier(0);
    __builtin_amdgcn_s_barrier();
    asm volatile("s_waitcnt lgkmcnt(0)" ::: "memory");
    __builtin_amdgcn_sched_barrier(0);
    __builtin_amdgcn_s_setprio(1);
#pragma unroll
    for (int mf = 0; mf < 4; ++mf)
#pragma unroll
      for (int nf = 0; nf < 4; ++nf)
        acc[4 + mf][nf] =
            __builtin_amdgcn_mfma_f32_16x16x32_bf16(af[mf], bf[nf], acc[4 + mf][nf], 0, 0, 0);
    __builtin_amdgcn_s_setprio(0);
    __builtin_amdgcn_sched_barrier(0);
    __builtin_amdgcn_s_barrier();
    __builtin_amdgcn_sched_barrier(0);
    c3 = (c3 == 2) ? 0 : c3 + 1;
  }

#pragma unroll
  for (int mf = 0; mf < 8; ++mf)
#pragma unroll
    for (int nf = 0; nf < 4; ++nf)
#pragma unroll
      for (int j = 0; j < 4; ++j) {
        size_t r = (size_t)(m0 + wm * 128 + mf * 16 + lg * 4 + j);
        int c = n0 + wn * 64 + nf * 16 + lr;
        if (OUT_F32)
          ((float*)Cp)[r * ldc + c] = acc[mf][nf][j];
        else
          ((u16*)Cp)[r * ldc + c] = f32_bf16(acc[mf][nf][j]);
      }
}

// ---------------- sliding-window flash attention (pipelined, 8 waves, 32x32 MFMA) ----
// (unchanged from round 21 — passing; Q-rope fused into the register Q load)
__global__ __launch_bounds__(512, 2) void k_attn(u16* __restrict__ QKV,
                                                 const float* __restrict__ cs,
                                                 const float* __restrict__ sn) {
  const int bx = blockIdx.x, h = blockIdx.y, b = blockIdx.z;
  const int qb = (b >= 2) ? 7 - bx : bx;        // cost-balanced remap
  const int tid = threadIdx.x;
  const int lane = tid & 63, w = tid >> 6;      // 8 waves
  const int l31 = lane & 31, hi = lane >> 5;
  const int kh = h >> 2;
  const int qs = qb * 256 + w * 32;
  __shared__ __align__(16) u16 Klds[2][64 * 128];  // [kv][d], swizzled, 2 buffers
  __shared__ __align__(16) u16 Vt[2][128 * 64];    // [d][kv], swizzled, 2 buffers
  const float SCL2 = 0.08838834764831845f * 1.4426950408889634f;  // scale*log2(e)
  const size_t bL = (size_t)b * L_S;
  const int q = qs + l31;
  const size_t rowQ = (bL + q) * QW + h * HD;
  // Q load + fused interleaved RoPE (d = ds*16+hi*8+j; pair f = d>>1)
  short8 qf[8];
#pragma unroll
  for (int ds = 0; ds < 8; ++ds) {
    short8 qr = *(const short8*)(QKV + rowQ + ds * 16 + hi * 8);
    const int f0 = ds * 8 + hi * 4;                   // first pair index (mult of 4)
    float4 c4 = *(const float4*)(cs + (size_t)q * 64 + f0);
    float4 s4 = *(const float4*)(sn + (size_t)q * 64 + f0);
    ushort8 qo;
#pragma unroll
    for (int e = 0; e < 4; ++e) {
      float xr = bf16_f32((u16)qr[2 * e]);
      float xi = bf16_f32((u16)qr[2 * e + 1]);
      float co = (e == 0) ? c4.x : (e == 1) ? c4.y : (e == 2) ? c4.z : c4.w;
      float si = (e == 0) ? s4.x : (e == 1) ? s4.y : (e == 2) ? s4.z : s4.w;
      qo[2 * e]     = f32_bf16(xr * co - xi * si);
      qo[2 * e + 1] = f32_bf16(xr * si + xi * co);
    }
    qf[ds] = __builtin_bit_cast(short8, qo);
  }
  f32x16 o[4];
#pragma unroll
  for (int dt = 0; dt < 4; ++dt)
#pragma unroll
    for (int r = 0; r < 16; ++r) o[dt][r] = 0.f;
  float m2 = -3e38f, lsum = 0.f;  // per-lane stats for this lane's q (log2 domain)
  int t0 = qb * 256 - (WIN - 1);
  if (t0 < 0) t0 = 0;
  t0 >>= 6;
  const int t1 = 4 * qb + 3;  // == (qb*256+255)>>6
  short8 vreg[2];

  auto ISSUE_K = [&](int t, int buf) {
    char* Kb = (char*)Klds + buf * 16384;
#pragma unroll
    for (int rr = 0; rr < 2; ++rr) {
      int row = rr * 32 + (tid >> 4);              // 0..63
      int colb = ((tid & 15) * 16) ^ ((row & 7) << 4);  // inverse-swizzled source
      gload_lds16(QKV + (bL + t * 64 + row) * QW + E_D + kh * HD + (colb >> 1),
                  Kb + rr * 8192 + w * 1024 + (lane << 4));
    }
  };
  auto LOAD_V = [&](int t) {
#pragma unroll
    for (int rr = 0; rr < 2; ++rr)
      vreg[rr] = *(const short8*)(QKV + (bL + t * 64 + lane) * QW + E_D + 512 + kh * HD +
                                  ((w * 2 + rr) * 8));
  };
  auto WRITE_V = [&](int buf) {
    char* Vb = (char*)Vt + buf * 16384;
#pragma unroll
    for (int rr = 0; rr < 2; ++rr) {
      int db = (w * 2 + rr) * 8;                   // multiple of 8 -> row&7 == e
#pragma unroll
      for (int e = 0; e < 8; ++e)
        *(u16*)(Vb + ((((db + e) * 128) + lane * 2) ^ (e << 4))) = (u16)vreg[rr][e];
    }
  };

  LOAD_V(t0);
  ISSUE_K(t0, 0);
  __syncthreads();          // drains K gloads + V reg loads
  WRITE_V(0);               // Vt[0] = V(t0); published by barrier1 of iter t0
  int c = 0;

  for (int t = t0; t <= t1; ++t) {
    const int kv0 = t * 64;
    const bool lastt = (t == t1);
    if (!lastt) {           // prefetch next tile: K -> Klds[c^1], V -> regs
      ISSUE_K(t + 1, c ^ 1);
      LOAD_V(t + 1);
    }
    const bool act = (kv0 <= qs + 31) && (kv0 + 63 > qs - WIN);
    const bool full = (kv0 + 63 <= qs) && (kv0 > qs + 31 - WIN);  // no masking needed
    u32x4 pa[4];  // assembled PV A-frags (bf16 x8 each)
    if (act) {
      char* Kb = (char*)Klds + c * 16384;
      f32x16 s[2];
#pragma unroll
      for (int g = 0; g < 2; ++g)
#pragma unroll
        for (int r = 0; r < 16; ++r) s[g][r] = 0.f;
#pragma unroll
      for (int g = 0; g < 2; ++g) {
        const int r = g * 32 + l31;                  // K row this lane reads
        const int rsw = (r & 7) << 4;
#pragma unroll
        for (int ds = 0; ds < 8; ++ds) {
          short8 kf = *(const short8*)(Kb + (r * 256 + ((ds * 32 + hi * 16) ^ rsw)));
          s[g] = __builtin_amdgcn_mfma_f32_32x32x16_bf16(kf, qf[ds], s[g], 0, 0, 0);
        }
      }
      float v[2][16];
      float mx = -3e38f;
      if (full) {
#pragma unroll
        for (int g = 0; g < 2; ++g)
#pragma unroll
          for (int r = 0; r < 16; ++r) {
            float vv = s[g][r] * SCL2;
            v[g][r] = vv;
            mx = fmaxf(mx, vv);
          }
      } else {
#pragma unroll
        for (int g = 0; g < 2; ++g)
#pragma unroll
          for (int r = 0; r < 16; ++r) {
            int kg = kv0 + g * 32 + (r & 3) + 8 * (r >> 2) + 4 * hi;
            bool a = (kg <= q) && (kg > q - WIN);
            float vv = a ? s[g][r] * SCL2 : -3e38f;
            v[g][r] = vv;
            mx = fmaxf(mx, vv);
          }
      }
      mx = fmaxf(mx, __shfl_xor(mx, 32));            // partner has other kv half
      if (__ballot(mx > m2 + 11.5415603f)) {
        float mn = fmaxf(m2, mx);
        float alpha = exp2f(m2 - mn);
        m2 = mn;
        lsum *= alpha;
#pragma unroll
        for (int r = 0; r < 16; ++r) {
          float alr = __shfl(alpha, (r & 3) + 8 * (r >> 2) + 4 * hi);
#pragma unroll
          for (int dt = 0; dt < 4; ++dt) o[dt][r] *= alr;
        }
      }
      float rs = 0.f;
      if (full) {
#pragma unroll
        for (int g = 0; g < 2; ++g)
#pragma unroll
          for (int r = 0; r < 16; ++r) {
            float pe = exp2f(v[g][r] - m2);
            v[g][r] = pe;
            rs += pe;
          }
      } else {
#pragma unroll
        for (int g = 0; g < 2; ++g)
#pragma unroll
          for (int r = 0; r < 16; ++r) {
            float pe = (v[g][r] > -1e37f) ? exp2f(v[g][r] - m2) : 0.f;
            v[g][r] = pe;
            rs += pe;
          }
      }
      rs += __shfl_xor(rs, 32);
      lsum += rs;
#pragma unroll
      for (int g = 0; g < 2; ++g) {
        u32 W[8];
#pragma unroll
        for (int qi = 0; qi < 4; ++qi) {
          W[2 * qi]     = pack_bf16_pair(v[g][4 * qi + 0], v[g][4 * qi + 1]);
          W[2 * qi + 1] = pack_bf16_pair(v[g][4 * qi + 2], v[g][4 * qi + 3]);
        }
        u32 R[4];
        R[0] = __shfl_xor(hi ? W[0] : W[2], 32);
        R[1] = __shfl_xor(hi ? W[1] : W[3], 32);
        R[2] = __shfl_xor(hi ? W[4] : W[6], 32);
        R[3] = __shfl_xor(hi ? W[5] : W[7], 32);
#pragma unroll
        for (int ksl = 0; ksl < 2; ++ksl) {
          u32x4 fr;
          if (hi == 0) {
            fr[0] = W[4 * ksl]; fr[1] = W[4 * ksl + 1];
            fr[2] = R[2 * ksl]; fr[3] = R[2 * ksl + 1];
          } else {
            fr[0] = R[2 * ksl]; fr[1] = R[2 * ksl + 1];
            fr[2] = W[4 * ksl + 2]; fr[3] = W[4 * ksl + 3];
          }
          pa[g * 2 + ksl] = fr;
        }
      }
    }
    __syncthreads();  // barrier1: drains K/V prefetch loads; publishes Vt[c]; orders reuse
    if (act) {
      // --- O += P V from Vt[c] (MFMA issues immediately after barrier) ---
      char* Vb = (char*)Vt + c * 16384;
      __builtin_amdgcn_s_setprio(1);
#pragma unroll
      for (int dt = 0; dt < 4; ++dt) {
        const int d = dt * 32 + l31;
        const int dsw = (d & 7) << 4;
#pragma unroll
        for (int ks = 0; ks < 4; ++ks) {
          short8 vf = *(const short8*)(Vb + (d * 128 + ((ks * 32 + hi * 16) ^ dsw)));
          o[dt] = __builtin_amdgcn_mfma_f32_32x32x16_bf16(
              __builtin_bit_cast(short8, pa[ks]), vf, o[dt], 0, 0, 0);
        }
      }
      __builtin_amdgcn_s_setprio(0);
    }
    if (!lastt) WRITE_V(c ^ 1);  // stage V(t+1); readers gated by barrier1(t+1)
    c ^= 1;
  }
  float inv = 1.0f / lsum;
#pragma unroll
  for (int r = 0; r < 16; ++r) {
    int ridx = (r & 3) + 8 * (r >> 2) + 4 * hi;
    float invr = __shfl(inv, ridx);
    size_t rowO = (bL + qs + ridx) * QW + h * HD + l31;
#pragma unroll
    for (int dt = 0; dt < 4; ++dt)
      QKV[rowO + dt * 32] = f32_bf16(o[dt][r] * invr);
  }
}

extern "C" void kernel_launch(void* const* d_in, const int* in_sizes, int n_in,
                              void* d_out, int out_size, void* d_ws, size_t ws_size,
                              hipStream_t stream) {
  const float* x  = (const float*)d_in[0];
  const float* Wq = (const float*)d_in[1];
  const float* Wk = (const float*)d_in[2];
  const float* Wv = (const float*)d_in[3];
  const float* Wo = (const float*)d_in[4];
  char* ws = (char*)d_ws;
  // Workspace layout (total 105,906,176 B). If the harness workspace is too
  // small, bail out cleanly (validation fails loudly instead of GPU faulting).
  if (ws_size < 105906176u) return;
  u16* xb    = (u16*)(ws);                    // 8192*2048*2 = 33554432
  u16* Wqkv  = (u16*)(ws + 33554432);         // 3072*2048*2 = 12582912
  u16* Wob   = (u16*)(ws + 46137344);         // 2048*2048*2 =  8388608
  u16* QKV   = (u16*)(ws + 54525952);         // 8192*3072*2 = 50331648
  float* cs  = (float*)(ws + 104857600);      // 131072*4    =   524288
  float* sn  = (float*)(ws + 105381888);      // total end 105906176 B

  // bf16 casts (weights packed: Wq rows 0..2047 | Wk rows 2048..2559 | Wv rows 2560..3071)
  k_cast<<<8192, 256, 0, stream>>>(x, xb, 16777216 / 8);
  k_cast<<<2048, 256, 0, stream>>>(Wq, Wqkv, 4194304 / 8);
  k_cast<<<512, 256, 0, stream>>>(Wk, Wqkv + 2048 * 2048, 1048576 / 8);
  k_cast<<<512, 256, 0, stream>>>(Wv, Wqkv + 2560 * 2048, 1048576 / 8);
  k_cast<<<2048, 256, 0, stream>>>(Wo, Wob, 4194304 / 8);
  k_rope_table<<<512, 256, 0, stream>>>(cs, sn);
  // fused QKV projection: [Q|K|V] = xb @ Wqkv^T (256^2 tiles: 32 m x 12 n = 384 wg)
  k_gemm8<0><<<384, 512, 0, stream>>>(xb, 2048, Wqkv, 2048, QKV, QW, 2048);
  // RoPE in place on K region only (Q rope fused into k_attn)
  k_rope_k<<<8192, 256, 0, stream>>>(QKV, cs, sn);
  // flash attention (Q-rope fused); Z overwrites Q region of QKV
  k_attn<<<dim3(8, 16, 4), 512, 0, stream>>>(QKV, cs, sn);
  // out = Z @ Wo^T (fp32 out; 32 m x 8 n = 256 wg)
  k_gemm8<1><<<256, 512, 0, stream>>>(QKV, QW, Wob, 2048, d_out, 2048, 2048);
}

// Round 23
// 369.175 us; speedup vs baseline: 1.2945x; 1.0184x over previous
//
#include <hip/hip_runtime.h>
#include <hip/hip_bf16.h>
#include <math.h>

typedef unsigned short u16;
typedef unsigned int u32;
typedef __attribute__((ext_vector_type(8))) short short8;
typedef __attribute__((ext_vector_type(8))) u16 ushort8;
typedef __attribute__((ext_vector_type(4))) float f32x4;
typedef __attribute__((ext_vector_type(16))) float f32x16;
typedef __attribute__((ext_vector_type(4))) u32 u32x4;

#define N_B 4
#define L_S 2048
#define E_D 2048
#define NH 16
#define HD 128
#define WIN 1024
#define QW 3072  // QKV buffer row width: 2048 q | 512 k | 512 v
#define LOG2E 1.4426950408889634f

static __device__ __forceinline__ u16 f32_bf16(float f) {
  u32 u = __builtin_bit_cast(u32, f);
  u = (u + 0x7fffu + ((u >> 16) & 1u)) >> 16;  // RNE
  return (u16)u;
}
static __device__ __forceinline__ float bf16_f32(u16 h) {
  u32 u = ((u32)h) << 16;
  return __builtin_bit_cast(float, u);
}
static __device__ __forceinline__ u32 pack_bf16_pair(float lo, float hi) {
  __hip_bfloat162 h2 = __float22bfloat162_rn(make_float2(lo, hi));  // RNE, .x = low
  u32 r;
  __builtin_memcpy(&r, &h2, 4);
  return r;
}
static __device__ __forceinline__ void gload_lds16(const void* g, void* l) {
  __builtin_amdgcn_global_load_lds((__attribute__((address_space(1))) void*)g,
                                   (__attribute__((address_space(3))) void*)l, 16, 0, 0);
}

// ---------------- fp32 -> bf16 cast (n multiple of 8) ----------------
__global__ void k_cast(const float* __restrict__ src, u16* __restrict__ dst, int n8) {
  int i = blockIdx.x * blockDim.x + threadIdx.x;
  if (i >= n8) return;
  const float4* s = (const float4*)src + (size_t)i * 2;
  float4 a = s[0], b = s[1];
  ushort8 v;
  v[0] = f32_bf16(a.x); v[1] = f32_bf16(a.y); v[2] = f32_bf16(a.z); v[3] = f32_bf16(a.w);
  v[4] = f32_bf16(b.x); v[5] = f32_bf16(b.y); v[6] = f32_bf16(b.z); v[7] = f32_bf16(b.w);
  *((ushort8*)dst + i) = v;
}

// ---------------- all 4 weight casts in one launch (block-range switch) -------------
// blocks [0,2048): Wq -> dst; [2048,2560): Wk -> dst+2048*2048; [2560,3072): Wv;
// [3072,5120): Wo -> dstWo. Each block = 256 thr x 8 elems = 2048 elems.
__global__ void k_cast_w(const float* __restrict__ Wq, const float* __restrict__ Wk,
                         const float* __restrict__ Wv, const float* __restrict__ Wo,
                         u16* __restrict__ Wqkv, u16* __restrict__ Wob) {
  int bb = blockIdx.x;
  const float* src;
  u16* dst;
  int base;
  if (bb < 2048)      { src = Wq; dst = Wqkv;                 base = bb; }
  else if (bb < 2560) { src = Wk; dst = Wqkv + 2048 * 2048;   base = bb - 2048; }
  else if (bb < 3072) { src = Wv; dst = Wqkv + 2560 * 2048;   base = bb - 2560; }
  else                { src = Wo; dst = Wob;                  base = bb - 3072; }
  int i = base * 256 + threadIdx.x;
  const float4* s = (const float4*)src + (size_t)i * 2;
  float4 a = s[0], b = s[1];
  ushort8 v;
  v[0] = f32_bf16(a.x); v[1] = f32_bf16(a.y); v[2] = f32_bf16(a.z); v[3] = f32_bf16(a.w);
  v[4] = f32_bf16(b.x); v[5] = f32_bf16(b.y); v[6] = f32_bf16(b.z); v[7] = f32_bf16(b.w);
  *((ushort8*)dst + i) = v;
}

// ---------------- RoPE cos/sin table: [L][64] ----------------
__global__ void k_rope_table(float* __restrict__ cs, float* __restrict__ sn) {
  int idx = blockIdx.x * blockDim.x + threadIdx.x;  // 2048*64
  int l = idx >> 6, f = idx & 63;
  float freq = exp2f(-(float)f * (13.287712379549449f / 64.0f));  // 10000^(-2f/128)
  float ang = (float)l * freq;
  cs[idx] = cosf(ang);
  sn[idx] = sinf(ang);
}

// ---------------- interleaved RoPE applied in place to K region of QKV --------------
__global__ void k_rope_k(u16* __restrict__ QKV, const float* __restrict__ cs,
                         const float* __restrict__ sn) {
  int idx = blockIdx.x * blockDim.x + threadIdx.x;  // 8192*4*64 exactly
  int f = idx & 63;
  int rest = idx >> 6;
  int hh = rest & 3;           // kv head 0..3
  int row = rest >> 2;         // 0..8191 (= n*L + l)
  int l = row & (L_S - 1);
  int col = E_D + hh * HD + 2 * f;
  u32* p = (u32*)(QKV + (size_t)row * QW + col);
  u32 v = *p;
  float xr = bf16_f32((u16)(v & 0xffffu));
  float xi = bf16_f32((u16)(v >> 16));
  float c = cs[l * 64 + f], s = sn[l * 64 + f];
  float orr = xr * c - xi * s;
  float oii = xr * s + xi * c;
  *p = (u32)f32_bf16(orr) | ((u32)f32_bf16(oii) << 16);
}

// ---------------- C = A @ B^T, 256x256 tile, BK=32, 8-phase counted-vmcnt ----
// (unchanged from round 22 — passing, improved over r16/r19)
template <int OUT_F32>
__global__ __launch_bounds__(512, 1) void k_gemm8(
    const u16* __restrict__ A, int lda,
    const u16* __restrict__ B, int ldb,
    void* __restrict__ Cp, int ldc, int K) {
  __shared__ __align__(16) u16 Ab[3 * 8192];  // 3 x [256][32]
  __shared__ __align__(16) u16 Bb[3 * 8192];
  const int tid = threadIdx.x;
  const int lane = tid & 63, w = tid >> 6;
  const int lr = lane & 15, lg = lane >> 4;
  const int wm = w >> 2, wn = w & 3;
  const int fid = blockIdx.x;
  const int cc = fid & 7, l = fid >> 3;
  const int m0 = (cc * 4 + (l & 3)) * 256;
  const int n0 = (l >> 2) * 256;
  const int rswz = (lr & 6) << 3;  // read-side XOR (row bits 1-2)

  const int r2 = tid >> 2;                                   // 0..127
  const int ce = (((tid & 3) * 16) ^ ((r2 & 6) << 3)) >> 1;  // pre-swizzled src col
  auto STAGE_A = [&](int kt, int bb) {
#pragma unroll
    for (int rr = 0; rr < 2; ++rr)
      gload_lds16(A + (size_t)(m0 + rr * 128 + r2) * lda + kt * 32 + ce,
                  (char*)Ab + bb * 16384 + rr * 8192 + (w << 10));
  };
  auto STAGE_B = [&](int kt, int bb) {
#pragma unroll
    for (int rr = 0; rr < 2; ++rr)
      gload_lds16(B + (size_t)(n0 + rr * 128 + r2) * ldb + kt * 32 + ce,
                  (char*)Bb + bb * 16384 + rr * 8192 + (w << 10));
  };

  f32x4 acc[8][4];
  const f32x4 z4 = {0.f, 0.f, 0.f, 0.f};
#pragma unroll
  for (int mf = 0; mf < 8; ++mf)
#pragma unroll
    for (int nf = 0; nf < 4; ++nf) acc[mf][nf] = z4;

  const int nt = K >> 5;  // K-tiles of 32 (K=2048 -> 64)
  STAGE_A(0, 0); STAGE_B(0, 0);
  STAGE_A(1, 1); STAGE_B(1, 1);
  asm volatile("s_waitcnt vmcnt(4)" ::: "memory");  // tile0 published; tile1 in flight
  __builtin_amdgcn_sched_barrier(0);
  __builtin_amdgcn_s_barrier();
  __builtin_amdgcn_sched_barrier(0);

  int c3 = 0;
  for (int t = 0; t < nt; ++t) {
    int ib = c3 + 2; if (ib >= 3) ib -= 3;
    const char* Abt = (const char*)Ab + c3 * 16384;
    const char* Bbt = (const char*)Bb + c3 * 16384;
    short8 af[4], bf[4];
    // ---- phase 0: quadrant qm=0 ----
#pragma unroll
    for (int nf = 0; nf < 4; ++nf) {
      int row = wn * 64 + nf * 16 + lr;
      bf[nf] = *(const short8*)(Bbt + row * 64 + ((lg * 16) ^ rswz));
    }
#pragma unroll
    for (int mf = 0; mf < 4; ++mf) {
      int row = wm * 128 + mf * 16 + lr;
      af[mf] = *(const short8*)(Abt + row * 64 + ((lg * 16) ^ rswz));
    }
    if (t + 2 < nt) STAGE_A(t + 2, ib);
    __builtin_amdgcn_sched_barrier(0);
    __builtin_amdgcn_s_barrier();
    asm volatile("s_waitcnt lgkmcnt(0)" ::: "memory");
    __builtin_amdgcn_sched_barrier(0);
    __builtin_amdgcn_s_setprio(1);
#pragma unroll
    for (int mf = 0; mf < 4; ++mf)
#pragma unroll
      for (int nf = 0; nf < 4; ++nf)
        acc[mf][nf] =
            __builtin_amdgcn_mfma_f32_16x16x32_bf16(af[mf], bf[nf], acc[mf][nf], 0, 0, 0);
    __builtin_amdgcn_s_setprio(0);
    __builtin_amdgcn_sched_barrier(0);
    __builtin_amdgcn_s_barrier();
    __builtin_amdgcn_sched_barrier(0);
    // ---- phase 1: quadrant qm=1 (bf carried in registers) ----
#pragma unroll
    for (int mf = 0; mf < 4; ++mf) {
      int row = wm * 128 + 64 + mf * 16 + lr;
      af[mf] = *(const short8*)(Abt + row * 64 + ((lg * 16) ^ rswz));
    }
    if (t + 2 < nt) STAGE_B(t + 2, ib);
    if (t + 2 < nt)
      asm volatile("s_waitcnt vmcnt(4)" ::: "memory");
    else
      asm volatile("s_waitcnt vmcnt(0)" ::: "memory");
    __builtin_amdgcn_sched_barrier(0);
    __builtin_amdgcn_s_barrier();
    asm volatile("s_waitcnt lgkmcnt(0)" ::: "memory");
    __builtin_amdgcn_sched_barrier(0);
    __builtin_amdgcn_s_setprio(1);
#pragma unroll
    for (int mf = 0; mf < 4; ++mf)
#pragma unroll
      for (int nf = 0; nf < 4; ++nf)
        acc[4 + mf][nf] =
            __builtin_amdgcn_mfma_f32_16x16x32_bf16(af[mf], bf[nf], acc[4 + mf][nf], 0, 0, 0);
    __builtin_amdgcn_s_setprio(0);
    __builtin_amdgcn_sched_barrier(0);
    __builtin_amdgcn_s_barrier();
    __builtin_amdgcn_sched_barrier(0);
    c3 = (c3 == 2) ? 0 : c3 + 1;
  }

#pragma unroll
  for (int mf = 0; mf < 8; ++mf)
#pragma unroll
    for (int nf = 0; nf < 4; ++nf)
#pragma unroll
      for (int j = 0; j < 4; ++j) {
        size_t r = (size_t)(m0 + wm * 128 + mf * 16 + lg * 4 + j);
        int c = n0 + wn * 64 + nf * 16 + lr;
        if (OUT_F32)
          ((float*)Cp)[r * ldc + c] = acc[mf][nf][j];
        else
          ((u16*)Cp)[r * ldc + c] = f32_bf16(acc[mf][nf][j]);
      }
}

// ---------------- sliding-window flash attention (4 waves, 128 q-rows/block) --------
// r23: q-blocks split 256->128 rows, grid (16,16,4) = 1024 blocks of 4 waves.
// Blocks <= 18 tile-iters; with 2 slots/CU the HW REFILLS finished slots ->
// sustained ~8 waves/CU instead of decaying (old: 512 blocks = exact capacity,
// no refill, makespan = worst pair of [4..20]-tile blocks). Heavy-first
// dispatch: qb = 15 - bx. Per-wave math (32x32 MFMA, P-in-reg, defer-max,
// fused Q-rope) identical to r22; only staging re-derived for 256 threads.
__global__ __launch_bounds__(256, 2) void k_attn(u16* __restrict__ QKV,
                                                 const float* __restrict__ cs,
                                                 const float* __restrict__ sn) {
  const int bx = blockIdx.x, h = blockIdx.y, b = blockIdx.z;
  const int qb = 15 - bx;                       // heavy blocks dispatch first
  const int tid = threadIdx.x;
  const int lane = tid & 63, w = tid >> 6;      // 4 waves
  const int l31 = lane & 31, hi = lane >> 5;
  const int kh = h >> 2;
  const int qs = qb * 128 + w * 32;
  __shared__ __align__(16) u16 Klds[2][64 * 128];  // [kv][d], swizzled, 2 buffers
  __shared__ __align__(16) u16 Vt[2][128 * 64];    // [d][kv], swizzled, 2 buffers
  const float SCL2 = 0.08838834764831845f * 1.4426950408889634f;  // scale*log2(e)
  const size_t bL = (size_t)b * L_S;
  const int q = qs + l31;
  const size_t rowQ = (bL + q) * QW + h * HD;
  // Q load + fused interleaved RoPE (d = ds*16+hi*8+j; pair f = d>>1)
  short8 qf[8];
#pragma unroll
  for (int ds = 0; ds < 8; ++ds) {
    short8 qr = *(const short8*)(QKV + rowQ + ds * 16 + hi * 8);
    const int f0 = ds * 8 + hi * 4;                   // first pair index (mult of 4)
    float4 c4 = *(const float4*)(cs + (size_t)q * 64 + f0);
    float4 s4 = *(const float4*)(sn + (size_t)q * 64 + f0);
    ushort8 qo;
#pragma unroll
    for (int e = 0; e < 4; ++e) {
      float xr = bf16_f32((u16)qr[2 * e]);
      float xi = bf16_f32((u16)qr[2 * e + 1]);
      float co = (e == 0) ? c4.x : (e == 1) ? c4.y : (e == 2) ? c4.z : c4.w;
      float si = (e == 0) ? s4.x : (e == 1) ? s4.y : (e == 2) ? s4.z : s4.w;
      qo[2 * e]     = f32_bf16(xr * co - xi * si);
      qo[2 * e + 1] = f32_bf16(xr * si + xi * co);
    }
    qf[ds] = __builtin_bit_cast(short8, qo);
  }
  f32x16 o[4];
#pragma unroll
  for (int dt = 0; dt < 4; ++dt)
#pragma unroll
    for (int r = 0; r < 16; ++r) o[dt][r] = 0.f;
  float m2 = -3e38f, lsum = 0.f;  // per-lane stats for this lane's q (log2 domain)
  int t0 = qb * 128 - (WIN - 1);
  if (t0 < 0) t0 = 0;
  t0 >>= 6;
  const int t1 = 2 * qb + 1;  // == (qb*128+127)>>6
  short8 vreg[4];

  // --- staging helpers (256 threads) ---
  auto ISSUE_K = [&](int t, int buf) {
    char* Kb = (char*)Klds + buf * 16384;
#pragma unroll
    for (int rr = 0; rr < 4; ++rr) {
      int row = rr * 16 + (tid >> 4);              // 0..63
      int colb = ((tid & 15) * 16) ^ ((row & 7) << 4);  // inverse-swizzled source
      gload_lds16(QKV + (bL + t * 64 + row) * QW + E_D + kh * HD + (colb >> 1),
                  Kb + rr * 4096 + w * 1024 + (lane << 4));
    }
  };
  auto LOAD_V = [&](int t) {
#pragma unroll
    for (int rr = 0; rr < 4; ++rr)
      vreg[rr] = *(const short8*)(QKV + (bL + t * 64 + lane) * QW + E_D + 512 + kh * HD +
                                  ((w * 4 + rr) * 8));
  };
  auto WRITE_V = [&](int buf) {
    char* Vb = (char*)Vt + buf * 16384;
#pragma unroll
    for (int rr = 0; rr < 4; ++rr) {
      int db = (w * 4 + rr) * 8;                   // multiple of 8 -> row&7 == e
#pragma unroll
      for (int e = 0; e < 8; ++e)
        *(u16*)(Vb + ((((db + e) * 128) + lane * 2) ^ (e << 4))) = (u16)vreg[rr][e];
    }
  };

  LOAD_V(t0);
  ISSUE_K(t0, 0);
  __syncthreads();          // drains K gloads + V reg loads
  WRITE_V(0);               // Vt[0] = V(t0); published by barrier1 of iter t0
  int c = 0;

  for (int t = t0; t <= t1; ++t) {
    const int kv0 = t * 64;
    const bool lastt = (t == t1);
    if (!lastt) {           // prefetch next tile: K -> Klds[c^1], V -> regs
      ISSUE_K(t + 1, c ^ 1);
      LOAD_V(t + 1);
    }
    const bool act = (kv0 <= qs + 31) && (kv0 + 63 > qs - WIN);
    const bool full = (kv0 + 63 <= qs) && (kv0 > qs + 31 - WIN);  // no masking needed
    u32x4 pa[4];  // assembled PV A-frags (bf16 x8 each)
    if (act) {
      char* Kb = (char*)Klds + c * 16384;
      f32x16 s[2];
#pragma unroll
      for (int g = 0; g < 2; ++g)
#pragma unroll
        for (int r = 0; r < 16; ++r) s[g][r] = 0.f;
#pragma unroll
      for (int g = 0; g < 2; ++g) {
        const int r = g * 32 + l31;                  // K row this lane reads
        const int rsw = (r & 7) << 4;
#pragma unroll
        for (int ds = 0; ds < 8; ++ds) {
          short8 kf = *(const short8*)(Kb + (r * 256 + ((ds * 32 + hi * 16) ^ rsw)));
          s[g] = __builtin_amdgcn_mfma_f32_32x32x16_bf16(kf, qf[ds], s[g], 0, 0, 0);
        }
      }
      float v[2][16];
      float mx = -3e38f;
      if (full) {
#pragma unroll
        for (int g = 0; g < 2; ++g)
#pragma unroll
          for (int r = 0; r < 16; ++r) {
            float vv = s[g][r] * SCL2;
            v[g][r] = vv;
            mx = fmaxf(mx, vv);
          }
      } else {
#pragma unroll
        for (int g = 0; g < 2; ++g)
#pragma unroll
          for (int r = 0; r < 16; ++r) {
            int kg = kv0 + g * 32 + (r & 3) + 8 * (r >> 2) + 4 * hi;
            bool a = (kg <= q) && (kg > q - WIN);
            float vv = a ? s[g][r] * SCL2 : -3e38f;
            v[g][r] = vv;
            mx = fmaxf(mx, vv);
          }
      }
      mx = fmaxf(mx, __shfl_xor(mx, 32));            // partner has other kv half
      if (__ballot(mx > m2 + 11.5415603f)) {
        float mn = fmaxf(m2, mx);
        float alpha = exp2f(m2 - mn);
        m2 = mn;
        lsum *= alpha;
#pragma unroll
        for (int r = 0; r < 16; ++r) {
          float alr = __shfl(alpha, (r & 3) + 8 * (r >> 2) + 4 * hi);
#pragma unroll
          for (int dt = 0; dt < 4; ++dt) o[dt][r] *= alr;
        }
      }
      float rs = 0.f;
      if (full) {
#pragma unroll
        for (int g = 0; g < 2; ++g)
#pragma unroll
          for (int r = 0; r < 16; ++r) {
            float pe = exp2f(v[g][r] - m2);
            v[g][r] = pe;
            rs += pe;
          }
      } else {
#pragma unroll
        for (int g = 0; g < 2; ++g)
#pragma unroll
          for (int r = 0; r < 16; ++r) {
            float pe = (v[g][r] > -1e37f) ? exp2f(v[g][r] - m2) : 0.f;
            v[g][r] = pe;
            rs += pe;
          }
      }
      rs += __shfl_xor(rs, 32);
      lsum += rs;
#pragma unroll
      for (int g = 0; g < 2; ++g) {
        u32 W[8];
#pragma unroll
        for (int qi = 0; qi < 4; ++qi) {
          W[2 * qi]     = pack_bf16_pair(v[g][4 * qi + 0], v[g][4 * qi + 1]);
          W[2 * qi + 1] = pack_bf16_pair(v[g][4 * qi + 2], v[g][4 * qi + 3]);
        }
        u32 R[4];
        R[0] = __shfl_xor(hi ? W[0] : W[2], 32);
        R[1] = __shfl_xor(hi ? W[1] : W[3], 32);
        R[2] = __shfl_xor(hi ? W[4] : W[6], 32);
        R[3] = __shfl_xor(hi ? W[5] : W[7], 32);
#pragma unroll
        for (int ksl = 0; ksl < 2; ++ksl) {
          u32x4 fr;
          if (hi == 0) {
            fr[0] = W[4 * ksl]; fr[1] = W[4 * ksl + 1];
            fr[2] = R[2 * ksl]; fr[3] = R[2 * ksl + 1];
          } else {
            fr[0] = R[2 * ksl]; fr[1] = R[2 * ksl + 1];
            fr[2] = W[4 * ksl + 2]; fr[3] = W[4 * ksl + 3];
          }
          pa[g * 2 + ksl] = fr;
        }
      }
    }
    __syncthreads();  // barrier1: drains K/V prefetch loads; publishes Vt[c]; orders reuse
    if (act) {
      // --- O += P V from Vt[c] (MFMA issues immediately after barrier) ---
      char* Vb = (char*)Vt + c * 16384;
      __builtin_amdgcn_s_setprio(1);
#pragma unroll
      for (int dt = 0; dt < 4; ++dt) {
        const int d = dt * 32 + l31;
        const int dsw = (d & 7) << 4;
#pragma unroll
        for (int ks = 0; ks < 4; ++ks) {
          short8 vf = *(const short8*)(Vb + (d * 128 + ((ks * 32 + hi * 16) ^ dsw)));
          o[dt] = __builtin_amdgcn_mfma_f32_32x32x16_bf16(
              __builtin_bit_cast(short8, pa[ks]), vf, o[dt], 0, 0, 0);
        }
      }
      __builtin_amdgcn_s_setprio(0);
    }
    if (!lastt) WRITE_V(c ^ 1);  // stage V(t+1); readers gated by barrier1(t+1)
    c ^= 1;
  }
  float inv = 1.0f / lsum;
#pragma unroll
  for (int r = 0; r < 16; ++r) {
    int ridx = (r & 3) + 8 * (r >> 2) + 4 * hi;
    float invr = __shfl(inv, ridx);
    size_t rowO = (bL + qs + ridx) * QW + h * HD + l31;
#pragma unroll
    for (int dt = 0; dt < 4; ++dt)
      QKV[rowO + dt * 32] = f32_bf16(o[dt][r] * invr);
  }
}

extern "C" void kernel_launch(void* const* d_in, const int* in_sizes, int n_in,
                              void* d_out, int out_size, void* d_ws, size_t ws_size,
                              hipStream_t stream) {
  const float* x  = (const float*)d_in[0];
  const float* Wq = (const float*)d_in[1];
  const float* Wk = (const float*)d_in[2];
  const float* Wv = (const float*)d_in[3];
  const float* Wo = (const float*)d_in[4];
  char* ws = (char*)d_ws;
  // Workspace layout (total 105,906,176 B). If the harness workspace is too
  // small, bail out cleanly (validation fails loudly instead of GPU faulting).
  if (ws_size < 105906176u) return;
  u16* xb    = (u16*)(ws);                    // 8192*2048*2 = 33554432
  u16* Wqkv  = (u16*)(ws + 33554432);         // 3072*2048*2 = 12582912
  u16* Wob   = (u16*)(ws + 46137344);         // 2048*2048*2 =  8388608
  u16* QKV   = (u16*)(ws + 54525952);         // 8192*3072*2 = 50331648
  float* cs  = (float*)(ws + 104857600);      // 131072*4    =   524288
  float* sn  = (float*)(ws + 105381888);      // total end 105906176 B

  // bf16 casts (weights packed: Wq rows 0..2047 | Wk rows 2048..2559 | Wv rows 2560..3071)
  k_cast<<<8192, 256, 0, stream>>>(x, xb, 16777216 / 8);
  k_cast_w<<<5120, 256, 0, stream>>>(Wq, Wk, Wv, Wo, Wqkv, Wob);
  k_rope_table<<<512, 256, 0, stream>>>(cs, sn);
  // fused QKV projection: [Q|K|V] = xb @ Wqkv^T (256^2 tiles: 32 m x 12 n = 384 wg)
  k_gemm8<0><<<384, 512, 0, stream>>>(xb, 2048, Wqkv, 2048, QKV, QW, 2048);
  // RoPE in place on K region only (Q rope fused into k_attn)
  k_rope_k<<<8192, 256, 0, stream>>>(QKV, cs, sn);
  // flash attention (Q-rope fused); Z overwrites Q region of QKV
  k_attn<<<dim3(16, 16, 4), 256, 0, stream>>>(QKV, cs, sn);
  // out = Z @ Wo^T (fp32 out; 32 m x 8 n = 256 wg)
  k_gemm8<1><<<256, 512, 0, stream>>>(QKV, QW, Wob, 2048, d_out, 2048, 2048);
}